// Round 3
// baseline (5556.487 us; speedup 1.0000x reference)
//
#include <hip/hip_runtime.h>
#include <cstdint>
#include <cstddef>

using u16 = unsigned short;
typedef short short8 __attribute__((ext_vector_type(8)));
typedef short short4v __attribute__((ext_vector_type(4)));
typedef float f32x4 __attribute__((ext_vector_type(4)));

#define LN_EPS 1e-5f
#define ATT_BETA 0.125f

__device__ __forceinline__ u16 f2bf(float f){
  uint32_t u = __float_as_uint(f);
  u += 0x7fffu + ((u >> 16) & 1u);
  return (u16)(u >> 16);
}
__device__ __forceinline__ float bf2f(u16 h){
  return __uint_as_float(((uint32_t)h) << 16);
}
__device__ __forceinline__ float wred_sum(float v){
  #pragma unroll
  for(int o=32;o;o>>=1) v += __shfl_xor(v,o,64);
  return v;
}
__device__ __forceinline__ void async16(const void* g, void* l){
  __builtin_amdgcn_global_load_lds((const __attribute__((address_space(1))) void*)g,
                                   (__attribute__((address_space(3))) void*)l, 16, 0, 0);
}

// ---------------- generic bf16 MFMA GEMM: C[M,N] = A[M,K] * B[N,K]^T (B row stride ldb) -------
// EPI: 1=bf16+relu out (row stride ldc), 2=t += alpha*acc (ATOMIC f32 — split-K safe),
//      3=encode epilogue, 4=decode epilogue,
//      5=dual store + transposed stores: col<768 -> Cb & QTo, col>=768 -> Cb2 & KTo
// ASPL: A operand split: k<768 from A, k>=768 from A2 (both row stride 768)
// Split-K: gridDim.z z-slices partition the K loop; only valid with EPI==2 (atomic accumulate).
template<int EPI, int ASPL>
__global__ __launch_bounds__(256)
void gemm_bt(const u16* __restrict__ A, const u16* __restrict__ A2,
             const u16* __restrict__ B,
             u16* __restrict__ Cb, u16* __restrict__ Cb2, float* __restrict__ Cf,
             int M, int N, int K, int ldb, int ldc,
             u16* __restrict__ QTo, u16* __restrict__ KTo,
             const float* __restrict__ aux0, const float* __restrict__ aux1,
             const float* __restrict__ araw, int blk)
{
  __shared__ u16 lA[128*32];
  __shared__ u16 lB[128*32];
  int tid = threadIdx.x;
  int w = tid >> 6, l = tid & 63;
  int wm = w >> 1, wn = w & 1;
  int m0 = blockIdx.y * 128, n0 = blockIdx.x * 128;
  int lr = l >> 2;           // row within 16-row chunk
  int lc = (l & 3) * 8;      // col (elements) within 32-wide K slab
  f32x4 acc[4][4];
  #pragma unroll
  for(int i=0;i<4;i++)
    #pragma unroll
    for(int j=0;j<4;j++) acc[i][j] = (f32x4){0.f,0.f,0.f,0.f};
  int fm = l & 15, fq = (l >> 4) * 8;

  int kn = K, k0 = 0;
  if(gridDim.z > 1){ kn = K / gridDim.z; k0 = blockIdx.z * kn; }

  for(int kt=k0; kt<k0+kn; kt+=32){
    __syncthreads();
    const u16* Asrc = A; int kcol = kt;
    if(ASPL){ if(kt >= 768){ Asrc = A2; kcol = kt - 768; } }
    int lda = ASPL ? 768 : K;
    #pragma unroll
    for(int c=0;c<2;c++){
      int rr = (w*2+c)*16;
      int ga = m0 + rr + lr; if(ga > M-1) ga = M-1;
      async16(Asrc + (size_t)ga*lda + kcol + lc, &lA[rr*32]);
      int gb = n0 + rr + lr; if(gb > N-1) gb = N-1;
      async16(B + (size_t)gb*ldb + kt + lc, &lB[rr*32]);
    }
    __syncthreads();
    short8 af[4], bfv[4];
    #pragma unroll
    for(int i=0;i<4;i++) af[i]  = *(const short8*)&lA[(wm*64 + i*16 + fm)*32 + fq];
    #pragma unroll
    for(int j=0;j<4;j++) bfv[j] = *(const short8*)&lB[(wn*64 + j*16 + fm)*32 + fq];
    #pragma unroll
    for(int i=0;i<4;i++)
      #pragma unroll
      for(int j=0;j<4;j++)
        acc[i][j] = __builtin_amdgcn_mfma_f32_16x16x32_bf16(af[i], bfv[j], acc[i][j], 0, 0, 0);
  }

  float alpha = 0.f;
  if(EPI==2) alpha = log1pf(__expf(araw[blk]));

  #pragma unroll
  for(int i=0;i<4;i++){
    int row_b = m0 + wm*64 + i*16 + (l>>4)*4;
    #pragma unroll
    for(int j=0;j<4;j++){
      int col = n0 + wn*64 + j*16 + (l&15);
      #pragma unroll
      for(int r=0;r<4;r++){
        int row = row_b + r;
        if(row >= M) continue;
        float v = acc[i][j][r];
        if(EPI==1){
          Cb[(size_t)row*ldc + col] = f2bf(v > 0.f ? v : 0.f);
        } else if(EPI==2){
          atomicAdd(&Cf[(size_t)row*768 + col], alpha * v);
        } else if(EPI==3){
          int pb = row / 196, pn = row - pb*196;
          Cf[((size_t)pb*197 + 1 + pn)*768 + col] = v + aux0[col] + aux1[(size_t)(1+pn)*768 + col];
        } else if(EPI==4){
          int pb = row / 197, rr2 = row - pb*197;
          if(rr2 > 0) Cf[((size_t)pb*196 + rr2 - 1)*768 + col] = v + aux0[col];
        } else { // EPI==5
          unsigned rw = (unsigned)row;
          unsigned pb = rw / 197u, jl = rw - pb*197u;
          u16 hv = f2bf(v);
          if(col < 768){
            Cb[(size_t)row*768 + col] = hv;
            QTo[(size_t)(pb*12u + (unsigned)(col>>6))*14336 + (size_t)(col&63)*224 + jl] = hv;
          } else {
            int c2 = col - 768;
            Cb2[(size_t)row*768 + c2] = hv;
            KTo[(size_t)(pb*12u + (unsigned)(c2>>6))*14336 + (size_t)(c2&63)*224 + jl] = hv;
          }
        }
      }
    }
  }
}

// ---------------- LN: mode 0 = EnergyLN (scalar gamma + per-dim bias), 1 = final LN ----------
// vectorized: 192 threads x f32x4 loads (768 = 192*4); waves 0-2 active on data, wave 3 idle.
__global__ __launch_bounds__(256)
void norm_k(const float* __restrict__ t, u16* __restrict__ out,
            const float* __restrict__ gv, const float* __restrict__ bv, int blk, int mode)
{
  __shared__ float r1[4], r2[4];
  int row = blockIdx.x;
  const float* tr = t + (size_t)row*768;
  int tid = threadIdx.x, w = tid>>6, l = tid&63;
  f32x4 v = (f32x4){0.f,0.f,0.f,0.f};
  float s=0.f, s2=0.f;
  if(tid < 192){
    v = ((const f32x4*)tr)[tid];
    s  = v[0]+v[1]+v[2]+v[3];
    s2 = v[0]*v[0]+v[1]*v[1]+v[2]*v[2]+v[3]*v[3];
  }
  s = wred_sum(s); s2 = wred_sum(s2);
  if(l==0){ r1[w]=s; r2[w]=s2; }
  __syncthreads();
  s  = r1[0]+r1[1]+r1[2]+r1[3];
  s2 = r2[0]+r2[1]+r2[2]+r2[3];
  float mu  = s * (1.0f/768.0f);
  float var = s2 * (1.0f/768.0f) - mu*mu;
  float rs  = rsqrtf(var + LN_EPS);
  u16* orow = out + (size_t)row*768;
  if(tid < 192){
    short4v o;
    if(mode==0){
      float gm = gv[blk];
      const float* bb = bv + blk*768;
      #pragma unroll
      for(int c=0;c<4;c++) o[c] = (short)f2bf((v[c]-mu)*rs*gm + bb[tid*4+c]);
    } else {
      #pragma unroll
      for(int c=0;c<4;c++) o[c] = (short)f2bf((v[c]-mu)*rs*gv[tid*4+c] + bv[tid*4+c]);
    }
    ((short4v*)orow)[tid] = o;
  }
}

// ---------------- legacy fused attention per (b,h) — fallback (non-merged ws) path only -------
__global__ __launch_bounds__(256)
void attn_k(u16* __restrict__ Qb, u16* __restrict__ Kb,
            const u16* __restrict__ QT, const u16* __restrict__ KT)
{
  __shared__ u16 P[32*256];      // 16,384 B
  __shared__ u16 PT[224*40];     // 17,920 B  (rows j=0..223, q stride 1, row stride 40)
  __shared__ float SredS[2][2][16];
  int bh = blockIdx.x, b = bh/12, h = bh - b*12;
  u16* Qg = Qb + (size_t)b*197*768 + h*64;
  u16* Kg = Kb + (size_t)b*197*768 + h*64;
  const u16* QTg = QT + (size_t)bh*14336;
  const u16* KTg = KT + (size_t)bh*14336;
  int tid = threadIdx.x, w = tid>>6, l = tid&63;
  int lane16 = l & 15, quad = l >> 4;
  int mt = w & 1, nh = w >> 1;
  int nt0 = nh*7, ncnt = nh ? 6 : 7;
  int jt0 = (w==0) ? 0 : (1 + 3*w);   // w0:{0..3} w1:{4..6} w2:{7..9} w3:{10..12}
  int jn  = (w==0) ? 4 : 3;

  f32x4 gk[4][4];
  #pragma unroll
  for(int a=0;a<4;a++)
    #pragma unroll
    for(int n2=0;n2<4;n2++) gk[a][n2] = (f32x4){0.f,0.f,0.f,0.f};

  for(int st=0; st<7; st++){
    int q0 = st*32;
    __syncthreads();   // protect P/PT/SredS rewrite vs previous stripe readers
    int qa = q0 + 16*mt + lane16; if(qa > 196) qa = 196;
    short8 a0 = *(const short8*)(Qg + (size_t)qa*768 + quad*8);
    short8 a1 = *(const short8*)(Qg + (size_t)qa*768 + 32 + quad*8);
    f32x4 sa[7];
    #pragma unroll
    for(int ni=0;ni<7;ni++) sa[ni] = (f32x4){0.f,0.f,0.f,0.f};
    for(int ni=0; ni<ncnt; ni++){
      int jb = (nt0+ni)*16 + lane16; if(jb > 196) jb = 196;
      short8 b0 = *(const short8*)(Kg + (size_t)jb*768 + quad*8);
      short8 b1 = *(const short8*)(Kg + (size_t)jb*768 + 32 + quad*8);
      sa[ni] = __builtin_amdgcn_mfma_f32_16x16x32_bf16(a0, b0, sa[ni],0,0,0);
      sa[ni] = __builtin_amdgcn_mfma_f32_16x16x32_bf16(a1, b1, sa[ni],0,0,0);
    }
    for(int ni=0; ni<ncnt; ni++){
      if((nt0+ni)*16 + lane16 > 196){
        sa[ni][0]=-3e38f; sa[ni][1]=-3e38f; sa[ni][2]=-3e38f; sa[ni][3]=-3e38f;
      }
    }
    float ss[4] = {0.f,0.f,0.f,0.f};
    for(int ni=0; ni<ncnt; ni++)
      #pragma unroll
      for(int r=0;r<4;r++){
        float e = __expf(fminf(ATT_BETA*sa[ni][r], 80.f));
        sa[ni][r] = e; ss[r] += e;
      }
    #pragma unroll
    for(int o=1;o<16;o<<=1)
      #pragma unroll
      for(int r=0;r<4;r++) ss[r] += __shfl_xor(ss[r], o, 64);
    if(lane16==0){
      #pragma unroll
      for(int r=0;r<4;r++) SredS[mt][nh][quad*4+r] = ss[r];
    }
    __syncthreads();
    float inv[4];
    #pragma unroll
    for(int r=0;r<4;r++) inv[r] = 1.f/(SredS[mt][0][quad*4+r] + SredS[mt][1][quad*4+r]);
    for(int ni=0; ni<ncnt; ni++){
      int j = (nt0+ni)*16 + lane16;
      short4v pk;
      #pragma unroll
      for(int r=0;r<4;r++){
        int q = 16*mt + quad*4 + r;
        float val = (q0 + q <= 196) ? sa[ni][r]*inv[r] : 0.f;
        u16 hv = f2bf(val);
        P[q*256 + 8*((j>>3)^(q&7)) + (j&7)] = hv;
        pk[r] = (short)hv;
      }
      *(short4v*)&PT[j*40 + 16*mt + 4*quad] = pk;
    }
    for(int idx=tid; idx<32*16; idx+=256){
      int q = idx>>4, j = 208 + (idx&15);
      P[q*256 + 8*((j>>3)^(q&7)) + (j&7)] = 0;
    }
    __syncthreads();
    {
      f32x4 gq[2]; gq[0] = (f32x4){0.f,0.f,0.f,0.f}; gq[1] = gq[0];
      int np0 = nh*2;
      int qrow = 16*mt + lane16;
      for(int kt=0; kt<7; kt++){
        short8 af = *(const short8*)&P[qrow*256 + 8*((4*kt+quad)^(qrow&7))];
        #pragma unroll
        for(int n2=0;n2<2;n2++){
          int z = (np0+n2)*16 + lane16;
          short8 bf8 = *(const short8*)(KTg + (size_t)z*224 + kt*32 + quad*8);
          gq[n2] = __builtin_amdgcn_mfma_f32_16x16x32_bf16(af, bf8, gq[n2],0,0,0);
        }
      }
      #pragma unroll
      for(int n2=0;n2<2;n2++)
        #pragma unroll
        for(int r=0;r<4;r++){
          int qg2 = q0 + 16*mt + quad*4 + r;
          if(qg2 <= 196) Qg[(size_t)qg2*768 + (np0+n2)*16 + lane16] = f2bf(gq[n2][r]);
        }
    }
    {
      short8 bq[4];
      #pragma unroll
      for(int n2=0;n2<4;n2++)
        bq[n2] = *(const short8*)(QTg + (size_t)(n2*16+lane16)*224 + q0 + quad*8);
      for(int ji=0; ji<jn; ji++){
        int j = (jt0+ji)*16 + lane16;
        short8 af = *(const short8*)&PT[j*40 + quad*8];
        #pragma unroll
        for(int n2=0;n2<4;n2++)
          gk[ji][n2] = __builtin_amdgcn_mfma_f32_16x16x32_bf16(af, bq[n2], gk[ji][n2],0,0,0);
      }
    }
  }
  __syncthreads();
  for(int ji=0; ji<jn; ji++){
    int jt = jt0 + ji;
    #pragma unroll
    for(int n2=0;n2<4;n2++)
      #pragma unroll
      for(int r=0;r<4;r++){
        int j = jt*16 + quad*4 + r;
        if(j <= 196) Kg[(size_t)j*768 + n2*16 + lane16] = f2bf(gk[ji][n2][r]);
      }
  }
}

// ---------------- 2-way stripe-split attention ------------------------------------------------
// Grid (768, 2). part 0 -> stripes 0..2 (q 0..95), part 1 -> stripes 3..6 (q 96..196).
// Same body as legacy attn_k, but:
//  - Gq written in-place to Qb (q-row ranges of the two parts are disjoint),
//  - partial Gk (197x64 f32) stored to Pk[part] instead of accumulating across all 7 stripes.
// red2_k then sums the two partials -> Kb (bf16).
__global__ __launch_bounds__(256)
void attn1_k(u16* __restrict__ Qb, const u16* __restrict__ Kb,
             const u16* __restrict__ QT, const u16* __restrict__ KT,
             float* __restrict__ Pk)
{
  __shared__ u16 P[32*256];      // 16,384 B
  __shared__ u16 PT[224*40];     // 17,920 B
  __shared__ float SredS[2][2][16];
  int bh = blockIdx.x, b = bh/12, h = bh - b*12;
  int part = blockIdx.y;
  u16* Qg = Qb + (size_t)b*197*768 + h*64;
  const u16* Kg = Kb + (size_t)b*197*768 + h*64;
  const u16* QTg = QT + (size_t)bh*14336;
  const u16* KTg = KT + (size_t)bh*14336;
  float* Pko = Pk + (size_t)part*9682944 + (size_t)b*197*768 + h*64;
  int tid = threadIdx.x, w = tid>>6, l = tid&63;
  int lane16 = l & 15, quad = l >> 4;
  int mt = w & 1, nh = w >> 1;
  int nt0 = nh*7, ncnt = nh ? 6 : 7;
  int jt0 = (w==0) ? 0 : (1 + 3*w);
  int jn  = (w==0) ? 4 : 3;
  int st0 = part ? 3 : 0, st1 = part ? 7 : 3;

  f32x4 gk[4][4];
  #pragma unroll
  for(int a=0;a<4;a++)
    #pragma unroll
    for(int n2=0;n2<4;n2++) gk[a][n2] = (f32x4){0.f,0.f,0.f,0.f};

  for(int st=st0; st<st1; st++){
    int q0 = st*32;
    __syncthreads();   // protect P/PT/SredS rewrite vs previous stripe readers
    int qa = q0 + 16*mt + lane16; if(qa > 196) qa = 196;
    short8 a0 = *(const short8*)(Qg + (size_t)qa*768 + quad*8);
    short8 a1 = *(const short8*)(Qg + (size_t)qa*768 + 32 + quad*8);
    f32x4 sa[7];
    #pragma unroll
    for(int ni=0;ni<7;ni++) sa[ni] = (f32x4){0.f,0.f,0.f,0.f};
    for(int ni=0; ni<ncnt; ni++){
      int jb = (nt0+ni)*16 + lane16; if(jb > 196) jb = 196;
      short8 b0 = *(const short8*)(Kg + (size_t)jb*768 + quad*8);
      short8 b1 = *(const short8*)(Kg + (size_t)jb*768 + 32 + quad*8);
      sa[ni] = __builtin_amdgcn_mfma_f32_16x16x32_bf16(a0, b0, sa[ni],0,0,0);
      sa[ni] = __builtin_amdgcn_mfma_f32_16x16x32_bf16(a1, b1, sa[ni],0,0,0);
    }
    for(int ni=0; ni<ncnt; ni++){
      if((nt0+ni)*16 + lane16 > 196){
        sa[ni][0]=-3e38f; sa[ni][1]=-3e38f; sa[ni][2]=-3e38f; sa[ni][3]=-3e38f;
      }
    }
    float ss[4] = {0.f,0.f,0.f,0.f};
    for(int ni=0; ni<ncnt; ni++)
      #pragma unroll
      for(int r=0;r<4;r++){
        float e = __expf(fminf(ATT_BETA*sa[ni][r], 80.f));
        sa[ni][r] = e; ss[r] += e;
      }
    #pragma unroll
    for(int o=1;o<16;o<<=1)
      #pragma unroll
      for(int r=0;r<4;r++) ss[r] += __shfl_xor(ss[r], o, 64);
    if(lane16==0){
      #pragma unroll
      for(int r=0;r<4;r++) SredS[mt][nh][quad*4+r] = ss[r];
    }
    __syncthreads();
    float inv[4];
    #pragma unroll
    for(int r=0;r<4;r++) inv[r] = 1.f/(SredS[mt][0][quad*4+r] + SredS[mt][1][quad*4+r]);
    for(int ni=0; ni<ncnt; ni++){
      int j = (nt0+ni)*16 + lane16;
      short4v pk;
      #pragma unroll
      for(int r=0;r<4;r++){
        int q = 16*mt + quad*4 + r;
        float val = (q0 + q <= 196) ? sa[ni][r]*inv[r] : 0.f;
        u16 hv = f2bf(val);
        P[q*256 + 8*((j>>3)^(q&7)) + (j&7)] = hv;
        pk[r] = (short)hv;
      }
      *(short4v*)&PT[j*40 + 16*mt + 4*quad] = pk;
    }
    for(int idx=tid; idx<32*16; idx+=256){
      int q = idx>>4, j = 208 + (idx&15);
      P[q*256 + 8*((j>>3)^(q&7)) + (j&7)] = 0;
    }
    __syncthreads();
    {
      f32x4 gq[2]; gq[0] = (f32x4){0.f,0.f,0.f,0.f}; gq[1] = gq[0];
      int np0 = nh*2;
      int qrow = 16*mt + lane16;
      for(int kt=0; kt<7; kt++){
        short8 af = *(const short8*)&P[qrow*256 + 8*((4*kt+quad)^(qrow&7))];
        #pragma unroll
        for(int n2=0;n2<2;n2++){
          int z = (np0+n2)*16 + lane16;
          short8 bf8 = *(const short8*)(KTg + (size_t)z*224 + kt*32 + quad*8);
          gq[n2] = __builtin_amdgcn_mfma_f32_16x16x32_bf16(af, bf8, gq[n2],0,0,0);
        }
      }
      #pragma unroll
      for(int n2=0;n2<2;n2++)
        #pragma unroll
        for(int r=0;r<4;r++){
          int qg2 = q0 + 16*mt + quad*4 + r;
          if(qg2 <= 196) Qg[(size_t)qg2*768 + (np0+n2)*16 + lane16] = f2bf(gq[n2][r]);
        }
    }
    {
      short8 bq[4];
      #pragma unroll
      for(int n2=0;n2<4;n2++)
        bq[n2] = *(const short8*)(QTg + (size_t)(n2*16+lane16)*224 + q0 + quad*8);
      for(int ji=0; ji<jn; ji++){
        int j = (jt0+ji)*16 + lane16;
        short8 af = *(const short8*)&PT[j*40 + quad*8];
        #pragma unroll
        for(int n2=0;n2<4;n2++)
          gk[ji][n2] = __builtin_amdgcn_mfma_f32_16x16x32_bf16(af, bq[n2], gk[ji][n2],0,0,0);
      }
    }
  }
  // partial Gk store (f32, clean per-part lines)
  for(int ji=0; ji<jn; ji++){
    int jt = jt0 + ji;
    #pragma unroll
    for(int n2=0;n2<4;n2++)
      #pragma unroll
      for(int r=0;r<4;r++){
        int j = jt*16 + quad*4 + r;
        if(j <= 196) Pko[(size_t)j*768 + n2*16 + lane16] = gk[ji][n2][r];
      }
  }
}

// ---------------- partial-Gk reduce: Kb = bf16(P0 + P1) ----------------------------------------
__global__ __launch_bounds__(256)
void red2_k(const float* __restrict__ P0, const float* __restrict__ P1,
            u16* __restrict__ o, int n4)
{
  for(int i=blockIdx.x*256+threadIdx.x; i<n4; i+=gridDim.x*256){
    f32x4 a = ((const f32x4*)P0)[i];
    f32x4 c = ((const f32x4*)P1)[i];
    short4v s;
    #pragma unroll
    for(int k=0;k<4;k++) s[k] = (short)f2bf(a[k]+c[k]);
    ((short4v*)o)[i] = s;
  }
}

// ---------------- small utility kernels ----------------
__global__ void cvt_k(const float* __restrict__ in, u16* __restrict__ out, int n){
  for(int i=blockIdx.x*256+threadIdx.x; i<n; i+=gridDim.x*256) out[i] = f2bf(in[i]);
}

// dst[c*dstride + coff + r] = bf16(src[r*C + c]); R,C multiples of 32
__global__ __launch_bounds__(256)
void tr_k(const float* __restrict__ src, u16* __restrict__ dst, int R, int C, int dstride, int coff){
  __shared__ float tile[32][33];
  int c0 = blockIdx.x*32, r0 = blockIdx.y*32;
  int tx = threadIdx.x & 31, ty = threadIdx.x >> 5;
  for(int i=ty;i<32;i+=8) tile[i][tx] = src[(size_t)(r0+i)*C + c0 + tx];
  __syncthreads();
  for(int i=ty;i<32;i+=8) dst[(size_t)(c0+i)*dstride + coff + r0 + tx] = f2bf(tile[tx][i]);
}

__global__ void fill_cls_k(float* __restrict__ t, const float* __restrict__ cls, const float* __restrict__ pos){
  int b = blockIdx.x;
  for(int i=threadIdx.x;i<768;i+=256) t[(size_t)b*197*768 + i] = cls[i] + pos[i];
}

// ---------------- launch ----------------
extern "C" void kernel_launch(void* const* d_in, const int* in_sizes, int n_in,
                              void* d_out, int out_size, void* d_ws, size_t ws_size,
                              hipStream_t stream){
  const float* x      = (const float*)d_in[0];
  const float* W_enc  = (const float*)d_in[1];
  const float* b_enc  = (const float*)d_in[2];
  const float* cls    = (const float*)d_in[3];
  const float* pos    = (const float*)d_in[4];
  const float* gamma  = (const float*)d_in[5];
  const float* bias   = (const float*)d_in[6];
  const float* Wq     = (const float*)d_in[7];
  const float* Wk     = (const float*)d_in[8];
  const float* Whn    = (const float*)d_in[9];
  const float* araw   = (const float*)d_in[10];
  const float* ln_g   = (const float*)d_in[11];
  const float* ln_b   = (const float*)d_in[12];
  const float* W_dec  = (const float*)d_in[13];
  const float* b_dec  = (const float*)d_in[14];
  float* out = (float*)d_out;
  (void)in_sizes; (void)n_in; (void)out_size;

  const int M  = 64*197;   // 12608
  const int MX = 64*196;   // 12544

  // ---- workspace ----
  char* p = (char*)d_ws;
  float* t   = (float*)p;  p += (size_t)M*768*4;        // 38.7 MB
  u16*   g   = (u16*)p;    p += (size_t)M*768*2;        // 19.4 MB (LN out)
  u16*   Qb  = (u16*)p;    p += (size_t)M*768*2;        // 19.4 MB (Q -> Gq in place; xb overlay)
  u16*   Kb  = (u16*)p;    p += (size_t)M*768*2;        // 19.4 MB (K -> Gk; WencT/WdecT overlay)
  u16*   QTb = (u16*)p;    p += (size_t)768*14336*2;    // 22.0 MB [bh][z][224]
  u16*   KTb = (u16*)p;    p += (size_t)768*14336*2;    // 22.0 MB
  size_t base = (size_t)(p - (char*)d_ws);
  if(base > ws_size) return;
  // merged-hopfield hidden buffer (77.46 MB) if it fits, else 2-chunk overlay on Qb/Kb.
  // During attention (merged path) the same region holds Pk: 2 x 12608 x 768 f32 partial-Gk
  // buffers (2 x 38.73 MB = 77.46 MB exactly). hidden is dead gemm<2> -> next gemm<1>.
  u16* hidden; int hop_merged;
  if(base + (size_t)M*3072*2 <= ws_size){ hidden = (u16*)(d_ws) + base/2; hop_merged = 1; }
  else { hidden = Qb; hop_merged = 0; }
  float* Pk = (float*)hidden;   // valid only when hop_merged

  // ---- weights live inside d_out (28.3 MB of 38.5 MB; fully dead before decode write) ----
  u16* Wall = (u16*)d_out;
  u16* Wqkb = Wall;               // 2 x [Wq(768 rows); Wk(768 rows)] x 768
  u16* WqkT = Wall + 2359296;     // 2 x 768 x [WqT | WkT] (stride 1536)
  u16* WhnT = Wall + 4718592;     // 2 x 3072 x 768
  u16* WhnB = Wall + 9437184;     // 2 x 768 x 3072 (row-major, ldb 3072)
  u16* xb    = Qb;                // encode-time overlay
  u16* WencT = Kb;                // encode-time overlay
  u16* WdecT = Kb;                // decode-time overlay

  // ---- weight prep ----
  for(int b=0;b<2;b++){
    cvt_k<<<512,256,0,stream>>>(Wq + (size_t)b*589824, Wqkb + (size_t)b*1179648, 589824);
    cvt_k<<<512,256,0,stream>>>(Wk + (size_t)b*589824, Wqkb + (size_t)b*1179648 + 589824, 589824);
    tr_k<<<dim3(24,24),256,0,stream>>>(Wq + (size_t)b*589824, WqkT + (size_t)b*1179648, 768,768, 1536, 0);
    tr_k<<<dim3(24,24),256,0,stream>>>(Wk + (size_t)b*589824, WqkT + (size_t)b*1179648, 768,768, 1536, 768);
    tr_k<<<dim3(96,24),256,0,stream>>>(Whn + (size_t)b*2359296, WhnT + (size_t)b*2359296, 768,3072, 768, 0);
    cvt_k<<<2048,256,0,stream>>>(Whn + (size_t)b*2359296, WhnB + (size_t)b*2359296, 2359296);
  }

  // ---- encode: t = [cls; x@W_enc + b_enc] + pos ----
  cvt_k<<<1024,256,0,stream>>>(x, xb, MX*768);
  tr_k<<<dim3(24,24),256,0,stream>>>(W_enc, WencT, 768,768, 768, 0);
  fill_cls_k<<<64,256,0,stream>>>(t, cls, pos);
  gemm_bt<3,0><<<dim3(6,98),256,0,stream>>>(xb, nullptr, WencT, nullptr, nullptr, t,
                                            MX, 768, 768, 768, 768, nullptr, nullptr,
                                            b_enc, pos, nullptr, 0);

  // ---- energy-descent blocks ----
  for(int blk=0; blk<2; blk++){
    for(int s=0; s<4; s++){
      norm_k<<<M,256,0,stream>>>(t, g, gamma, bias, blk, 0);
      if(hop_merged){
        gemm_bt<1,0><<<dim3(24,99),256,0,stream>>>(g, nullptr,
            WhnT + (size_t)blk*2359296,
            hidden, nullptr, nullptr, M, 3072, 768, 768, 3072, nullptr, nullptr,
            nullptr, nullptr, nullptr, 0);
        gemm_bt<2,0><<<dim3(6,99,2),256,0,stream>>>(hidden, nullptr,
            WhnB + (size_t)blk*2359296,
            nullptr, nullptr, t, M, 768, 3072, 3072, 768, nullptr, nullptr,
            nullptr, nullptr, araw, blk);
      } else {
        for(int c=0;c<2;c++){
          gemm_bt<1,0><<<dim3(12,99),256,0,stream>>>(g, nullptr,
              WhnT + (size_t)blk*2359296 + (size_t)c*1536*768,
              hidden, nullptr, nullptr, M, 1536, 768, 768, 1536, nullptr, nullptr,
              nullptr, nullptr, nullptr, 0);
          gemm_bt<2,0><<<dim3(6,99,2),256,0,stream>>>(hidden, nullptr,
              WhnB + (size_t)blk*2359296 + (size_t)c*1536,
              nullptr, nullptr, t, M, 768, 1536, 3072, 768, nullptr, nullptr,
              nullptr, nullptr, araw, blk);
        }
      }
      // Q,K projection (dual store row-major + transposed QT/KT)
      gemm_bt<5,0><<<dim3(12,99),256,0,stream>>>(g, nullptr, Wqkb + (size_t)blk*1179648,
            Qb, Kb, nullptr, M, 1536, 768, 768, 768, QTb, KTb,
            nullptr, nullptr, nullptr, 0);
      if(hop_merged){
        // 2-way stripe-split attention: Gq in-place into Qb, partial Gk -> Pk (hidden overlay)
        attn1_k<<<dim3(768,2),256,0,stream>>>(Qb, Kb, QTb, KTb, Pk);
        red2_k<<<2048,256,0,stream>>>(Pk, Pk + 9682944, Kb, 2420736);
      } else {
        // fallback: legacy in-place fused attention (no Pk space)
        attn_k<<<768,256,0,stream>>>(Qb, Kb, QTb, KTb);
      }
      // gradient projection (merged K=1536, split-K z=2, split-A: A=Gq(Qb), A2=Gk(Kb))
      gemm_bt<2,1><<<dim3(6,99,2),256,0,stream>>>(Qb, Kb, WqkT + (size_t)blk*1179648,
            nullptr, nullptr, t, M, 768, 1536, 1536, 768, nullptr, nullptr,
            nullptr, nullptr, araw, blk);
    }
  }

  // ---- decode: LN -> GEMM -> drop CLS ----
  tr_k<<<dim3(24,24),256,0,stream>>>(W_dec, WdecT, 768,768, 768, 0);
  norm_k<<<M,256,0,stream>>>(t, g, ln_g, ln_b, 0, 1);
  gemm_bt<4,0><<<dim3(6,99),256,0,stream>>>(g, nullptr, WdecT, nullptr, nullptr, out,
                                            M, 768, 768, 768, 768, nullptr, nullptr,
                                            b_dec, nullptr, nullptr, 0);
}

// Round 4
// 5512.534 us; speedup vs baseline: 1.0080x; 1.0080x over previous
//
#include <hip/hip_runtime.h>
#include <cstdint>
#include <cstddef>

using u16 = unsigned short;
typedef short short8 __attribute__((ext_vector_type(8)));
typedef short short4v __attribute__((ext_vector_type(4)));
typedef float f32x4 __attribute__((ext_vector_type(4)));

#define LN_EPS 1e-5f
#define ATT_BETA 0.125f

__device__ __forceinline__ u16 f2bf(float f){
  uint32_t u = __float_as_uint(f);
  u += 0x7fffu + ((u >> 16) & 1u);
  return (u16)(u >> 16);
}
__device__ __forceinline__ float bf2f(u16 h){
  return __uint_as_float(((uint32_t)h) << 16);
}
__device__ __forceinline__ float wred_sum(float v){
  #pragma unroll
  for(int o=32;o;o>>=1) v += __shfl_xor(v,o,64);
  return v;
}
__device__ __forceinline__ void async16(const void* g, void* l){
  __builtin_amdgcn_global_load_lds((const __attribute__((address_space(1))) void*)g,
                                   (__attribute__((address_space(3))) void*)l, 16, 0, 0);
}

// ---------------- generic bf16 MFMA GEMM: C[M,N] = A[M,K] * B[N,K]^T (B row stride ldb) -------
// EPI: 1=bf16+relu out (row stride ldc), 2=t += alpha*acc (plain RMW), 3=encode epilogue,
//      4=decode epilogue
// ASPL: A operand split: k<768 from A, k>=768 from A2 (both row stride 768)
template<int EPI, int ASPL>
__global__ __launch_bounds__(256)
void gemm_bt(const u16* __restrict__ A, const u16* __restrict__ A2,
             const u16* __restrict__ B,
             u16* __restrict__ Cb, float* __restrict__ Cf,
             int M, int N, int K, int ldb, int ldc,
             const float* __restrict__ aux0, const float* __restrict__ aux1,
             const float* __restrict__ araw, int blk)
{
  __shared__ u16 lA[128*32];
  __shared__ u16 lB[128*32];
  int tid = threadIdx.x;
  int w = tid >> 6, l = tid & 63;
  int wm = w >> 1, wn = w & 1;
  int m0 = blockIdx.y * 128, n0 = blockIdx.x * 128;
  int lr = l >> 2;           // row within 16-row chunk
  int lc = (l & 3) * 8;      // col (elements) within 32-wide K slab
  f32x4 acc[4][4];
  #pragma unroll
  for(int i=0;i<4;i++)
    #pragma unroll
    for(int j=0;j<4;j++) acc[i][j] = (f32x4){0.f,0.f,0.f,0.f};
  int fm = l & 15, fq = (l >> 4) * 8;

  for(int kt=0; kt<K; kt+=32){
    __syncthreads();
    const u16* Asrc = A; int kcol = kt;
    if(ASPL){ if(kt >= 768){ Asrc = A2; kcol = kt - 768; } }
    int lda = ASPL ? 768 : K;
    #pragma unroll
    for(int c=0;c<2;c++){
      int rr = (w*2+c)*16;
      int ga = m0 + rr + lr; if(ga > M-1) ga = M-1;
      async16(Asrc + (size_t)ga*lda + kcol + lc, &lA[rr*32]);
      int gb = n0 + rr + lr; if(gb > N-1) gb = N-1;
      async16(B + (size_t)gb*ldb + kt + lc, &lB[rr*32]);
    }
    __syncthreads();
    short8 af[4], bfv[4];
    #pragma unroll
    for(int i=0;i<4;i++) af[i]  = *(const short8*)&lA[(wm*64 + i*16 + fm)*32 + fq];
    #pragma unroll
    for(int j=0;j<4;j++) bfv[j] = *(const short8*)&lB[(wn*64 + j*16 + fm)*32 + fq];
    #pragma unroll
    for(int i=0;i<4;i++)
      #pragma unroll
      for(int j=0;j<4;j++)
        acc[i][j] = __builtin_amdgcn_mfma_f32_16x16x32_bf16(af[i], bfv[j], acc[i][j], 0, 0, 0);
  }

  float alpha = 0.f;
  if(EPI==2) alpha = log1pf(__expf(araw[blk]));

  #pragma unroll
  for(int i=0;i<4;i++){
    int row_b = m0 + wm*64 + i*16 + (l>>4)*4;
    #pragma unroll
    for(int j=0;j<4;j++){
      int col = n0 + wn*64 + j*16 + (l&15);
      #pragma unroll
      for(int r=0;r<4;r++){
        int row = row_b + r;
        if(row >= M) continue;
        float v = acc[i][j][r];
        if(EPI==1){
          Cb[(size_t)row*ldc + col] = f2bf(v > 0.f ? v : 0.f);
        } else if(EPI==2){
          Cf[(size_t)row*768 + col] += alpha * v;
        } else if(EPI==3){
          int pb = row / 196, pn = row - pb*196;
          Cf[((size_t)pb*197 + 1 + pn)*768 + col] = v + aux0[col] + aux1[(size_t)(1+pn)*768 + col];
        } else { // EPI==4
          int pb = row / 197, rr2 = row - pb*197;
          if(rr2 > 0) Cf[((size_t)pb*196 + rr2 - 1)*768 + col] = v + aux0[col];
        }
      }
    }
  }
}

// ---------------- LN: mode 0 = EnergyLN (scalar gamma + per-dim bias), 1 = final LN ----------
// vectorized: 192 threads x f32x4 loads (768 = 192*4)
__global__ __launch_bounds__(256)
void norm_k(const float* __restrict__ t, u16* __restrict__ out,
            const float* __restrict__ gv, const float* __restrict__ bv, int blk, int mode)
{
  __shared__ float r1[4], r2[4];
  int row = blockIdx.x;
  const float* tr = t + (size_t)row*768;
  int tid = threadIdx.x, w = tid>>6, l = tid&63;
  f32x4 v = (f32x4){0.f,0.f,0.f,0.f};
  float s=0.f, s2=0.f;
  if(tid < 192){
    v = ((const f32x4*)tr)[tid];
    s  = v[0]+v[1]+v[2]+v[3];
    s2 = v[0]*v[0]+v[1]*v[1]+v[2]*v[2]+v[3]*v[3];
  }
  s = wred_sum(s); s2 = wred_sum(s2);
  if(l==0){ r1[w]=s; r2[w]=s2; }
  __syncthreads();
  s  = r1[0]+r1[1]+r1[2]+r1[3];
  s2 = r2[0]+r2[1]+r2[2]+r2[3];
  float mu  = s * (1.0f/768.0f);
  float var = s2 * (1.0f/768.0f) - mu*mu;
  float rs  = rsqrtf(var + LN_EPS);
  u16* orow = out + (size_t)row*768;
  if(tid < 192){
    short4v o;
    if(mode==0){
      float gm = gv[blk];
      const float* bb = bv + blk*768;
      #pragma unroll
      for(int c=0;c<4;c++) o[c] = (short)f2bf((v[c]-mu)*rs*gm + bb[tid*4+c]);
    } else {
      #pragma unroll
      for(int c=0;c<4;c++) o[c] = (short)f2bf((v[c]-mu)*rs*gv[tid*4+c] + bv[tid*4+c]);
    }
    ((short4v*)orow)[tid] = o;
  }
}

// ---------------- fused QK-projection + attention per (b,h) -----------------------------------
// Grid 768. Phase A: Q = g Wq^T, K = g Wk^T via MFMA (A=g rows, B=W rows), outputs written to
// LDS in BOTH row-major ([208][72] pad) and transposed ([64][232] pad) layouts straight from
// the accumulators. Phase B: legacy attention body (scores -> no-max softmax -> Gq = P K,
// Gk += P^T Q accumulated over stripes), with ALL Q/K/QT/KT reads served from LDS.
// Only global traffic: read g + Wqk (L2-resident via XCD swizzle), write Gq/Gk.
__global__ __launch_bounds__(256)
void attn_fused(const u16* __restrict__ g, const u16* __restrict__ Wqk,
                u16* __restrict__ GqO, u16* __restrict__ GkO)
{
  __shared__ u16 Qlds[208*72];   // 29,952 B  row q stride 72 (144B, 16B-aligned)
  __shared__ u16 Klds[208*72];   // 29,952 B
  __shared__ u16 QTl[64*232];    // 29,696 B  row z stride 232 (464B, 16B-aligned)
  __shared__ u16 KTl[64*232];    // 29,696 B
  __shared__ u16 P[32*256];      // 16,384 B  swizzled row-major P
  __shared__ u16 PT[224*40];     // 17,920 B
  __shared__ float SredS[2][2][16];
  // total 153,856 B < 160 KiB -> 1 block/CU

  int bhw = blockIdx.x;
  int bh = (bhw & 7)*96 + (bhw >> 3);   // bijective XCD chunk swizzle (768 % 8 == 0):
                                        // all 12 heads of a batch land on one XCD's L2
  int b = bh/12, h = bh - b*12;
  const u16* grows = g + (size_t)b*197*768;
  u16* Qg = GqO + (size_t)b*197*768 + h*64;
  u16* Kg = GkO + (size_t)b*197*768 + h*64;
  int tid = threadIdx.x, w = tid>>6, l = tid&63;
  int lane16 = l & 15, quad = l >> 4;

  // zero transposed-pad cols 208..231 (read by Gq kt=6 / Gk st=6 upper quads)
  for(int idx=tid; idx<64*24; idx+=256){
    int z = idx/24, c = 208 + (idx - (idx/24)*24);
    QTl[z*232 + c] = 0; KTl[z*232 + c] = 0;
  }

  // ---- phase A: projection. waves 0,1 -> Q (n-tiles 0..1 / 2..3); waves 2,3 -> K.
  {
    int half = w >> 1;            // 0=Q, 1=K
    int nt0  = (w & 1) * 2;
    const u16* Wb = Wqk + (size_t)half*589824 + (size_t)(h*64)*768;
    u16* Lr = half ? Klds : Qlds;
    u16* Lt = half ? KTl  : QTl;
    f32x4 acc[13][2];
    #pragma unroll
    for(int rt=0;rt<13;rt++){ acc[rt][0]=(f32x4){0.f,0.f,0.f,0.f}; acc[rt][1]=acc[rt][0]; }
    for(int kt=0; kt<24; kt++){
      int ko = kt*32 + quad*8;
      short8 b0 = *(const short8*)(Wb + (size_t)((nt0  )*16 + lane16)*768 + ko);
      short8 b1 = *(const short8*)(Wb + (size_t)((nt0+1)*16 + lane16)*768 + ko);
      #pragma unroll
      for(int rt=0; rt<13; rt++){
        int gr = rt*16 + lane16; if(gr > 196) gr = 196;
        short8 af = *(const short8*)(grows + (size_t)gr*768 + ko);
        acc[rt][0] = __builtin_amdgcn_mfma_f32_16x16x32_bf16(af, b0, acc[rt][0],0,0,0);
        acc[rt][1] = __builtin_amdgcn_mfma_f32_16x16x32_bf16(af, b1, acc[rt][1],0,0,0);
      }
    }
    #pragma unroll
    for(int rt=0; rt<13; rt++)
      #pragma unroll
      for(int n2=0; n2<2; n2++)
        #pragma unroll
        for(int r=0; r<4; r++){
          int q = rt*16 + quad*4 + r;       // D-layout: row=(l>>4)*4+r
          int z = (nt0+n2)*16 + lane16;     //           col=l&15
          u16 hv = f2bf(acc[rt][n2][r]);
          Lr[q*72  + z] = hv;
          Lt[z*232 + q] = hv;
        }
  }
  __syncthreads();

  // ---- phase B: legacy attention body, LDS-sourced
  int mt = w & 1, nh = w >> 1;
  int nt0s = nh*7, ncnt = nh ? 6 : 7;
  int jt0 = (w==0) ? 0 : (1 + 3*w);   // w0:{0..3} w1:{4..6} w2:{7..9} w3:{10..12}
  int jn  = (w==0) ? 4 : 3;

  f32x4 gk[4][4];
  #pragma unroll
  for(int a=0;a<4;a++)
    #pragma unroll
    for(int n2=0;n2<4;n2++) gk[a][n2] = (f32x4){0.f,0.f,0.f,0.f};

  for(int st=0; st<7; st++){
    int q0 = st*32;
    __syncthreads();   // protect P/PT/SredS rewrite vs previous stripe readers
    int qa = q0 + 16*mt + lane16; if(qa > 196) qa = 196;
    short8 a0 = *(const short8*)&Qlds[qa*72 + quad*8];
    short8 a1 = *(const short8*)&Qlds[qa*72 + 32 + quad*8];
    f32x4 sa[7];
    #pragma unroll
    for(int ni=0;ni<7;ni++) sa[ni] = (f32x4){0.f,0.f,0.f,0.f};
    for(int ni=0; ni<ncnt; ni++){
      int jb = (nt0s+ni)*16 + lane16; if(jb > 196) jb = 196;
      short8 b0 = *(const short8*)&Klds[jb*72 + quad*8];
      short8 b1 = *(const short8*)&Klds[jb*72 + 32 + quad*8];
      sa[ni] = __builtin_amdgcn_mfma_f32_16x16x32_bf16(a0, b0, sa[ni],0,0,0);
      sa[ni] = __builtin_amdgcn_mfma_f32_16x16x32_bf16(a1, b1, sa[ni],0,0,0);
    }
    for(int ni=0; ni<ncnt; ni++){
      if((nt0s+ni)*16 + lane16 > 196){
        sa[ni][0]=-3e38f; sa[ni][1]=-3e38f; sa[ni][2]=-3e38f; sa[ni][3]=-3e38f;
      }
    }
    // no-max softmax (beta=0.125, logits bounded; arg clamped)
    float ss[4] = {0.f,0.f,0.f,0.f};
    for(int ni=0; ni<ncnt; ni++)
      #pragma unroll
      for(int r=0;r<4;r++){
        float e = __expf(fminf(ATT_BETA*sa[ni][r], 80.f));
        sa[ni][r] = e; ss[r] += e;
      }
    #pragma unroll
    for(int o=1;o<16;o<<=1)
      #pragma unroll
      for(int r=0;r<4;r++) ss[r] += __shfl_xor(ss[r], o, 64);
    if(lane16==0){
      #pragma unroll
      for(int r=0;r<4;r++) SredS[mt][nh][quad*4+r] = ss[r];
    }
    __syncthreads();
    float inv[4];
    #pragma unroll
    for(int r=0;r<4;r++) inv[r] = 1.f/(SredS[mt][0][quad*4+r] + SredS[mt][1][quad*4+r]);
    // write P (swizzled) + PT (packed b64); rows q>196 forced 0
    for(int ni=0; ni<ncnt; ni++){
      int j = (nt0s+ni)*16 + lane16;
      short4v pk;
      #pragma unroll
      for(int r=0;r<4;r++){
        int q = 16*mt + quad*4 + r;
        float val = (q0 + q <= 196) ? sa[ni][r]*inv[r] : 0.f;
        u16 hv = f2bf(val);
        P[q*256 + 8*((j>>3)^(q&7)) + (j&7)] = hv;
        pk[r] = (short)hv;
      }
      *(short4v*)&PT[j*40 + 16*mt + 4*quad] = pk;
    }
    // zero P logical cols 208..223 (read by Gq kt=6 upper quads)
    for(int idx=tid; idx<32*16; idx+=256){
      int q = idx>>4, j = 208 + (idx&15);
      P[q*256 + 8*((j>>3)^(q&7)) + (j&7)] = 0;
    }
    __syncthreads();
    // ---- Gq = P K : B-frags from KTl (LDS)
    {
      f32x4 gq[2]; gq[0] = (f32x4){0.f,0.f,0.f,0.f}; gq[1] = gq[0];
      int np0 = nh*2;
      int qrow = 16*mt + lane16;
      for(int kt=0; kt<7; kt++){
        short8 af = *(const short8*)&P[qrow*256 + 8*((4*kt+quad)^(qrow&7))];
        #pragma unroll
        for(int n2=0;n2<2;n2++){
          int z = (np0+n2)*16 + lane16;
          short8 bf8 = *(const short8*)&KTl[z*232 + kt*32 + quad*8];
          gq[n2] = __builtin_amdgcn_mfma_f32_16x16x32_bf16(af, bf8, gq[n2],0,0,0);
        }
      }
      #pragma unroll
      for(int n2=0;n2<2;n2++)
        #pragma unroll
        for(int r=0;r<4;r++){
          int qg2 = q0 + 16*mt + quad*4 + r;
          if(qg2 <= 196) Qg[(size_t)qg2*768 + (np0+n2)*16 + lane16] = f2bf(gq[n2][r]);
        }
    }
    // ---- Gk accumulate: A-frags from PT, B-frags from QTl (LDS)
    {
      short8 bq[4];
      #pragma unroll
      for(int n2=0;n2<4;n2++)
        bq[n2] = *(const short8*)&QTl[(n2*16+lane16)*232 + q0 + quad*8];
      for(int ji=0; ji<jn; ji++){
        int j = (jt0+ji)*16 + lane16;
        short8 af = *(const short8*)&PT[j*40 + quad*8];
        #pragma unroll
        for(int n2=0;n2<4;n2++)
          gk[ji][n2] = __builtin_amdgcn_mfma_f32_16x16x32_bf16(af, bq[n2], gk[ji][n2],0,0,0);
      }
    }
  }
  __syncthreads();
  for(int ji=0; ji<jn; ji++){
    int jt = jt0 + ji;
    #pragma unroll
    for(int n2=0;n2<4;n2++)
      #pragma unroll
      for(int r=0;r<4;r++){
        int j = jt*16 + quad*4 + r;
        if(j <= 196) Kg[(size_t)j*768 + n2*16 + lane16] = f2bf(gk[ji][n2][r]);
      }
  }
}

// ---------------- small utility kernels ----------------
__global__ void cvt_k(const float* __restrict__ in, u16* __restrict__ out, int n){
  for(int i=blockIdx.x*256+threadIdx.x; i<n; i+=gridDim.x*256) out[i] = f2bf(in[i]);
}

// dst[c*dstride + coff + r] = bf16(src[r*C + c]); R,C multiples of 32
__global__ __launch_bounds__(256)
void tr_k(const float* __restrict__ src, u16* __restrict__ dst, int R, int C, int dstride, int coff){
  __shared__ float tile[32][33];
  int c0 = blockIdx.x*32, r0 = blockIdx.y*32;
  int tx = threadIdx.x & 31, ty = threadIdx.x >> 5;
  for(int i=ty;i<32;i+=8) tile[i][tx] = src[(size_t)(r0+i)*C + c0 + tx];
  __syncthreads();
  for(int i=ty;i<32;i+=8) dst[(size_t)(c0+i)*dstride + coff + r0 + tx] = f2bf(tile[tx][i]);
}

__global__ void fill_cls_k(float* __restrict__ t, const float* __restrict__ cls, const float* __restrict__ pos){
  int b = blockIdx.x;
  for(int i=threadIdx.x;i<768;i+=256) t[(size_t)b*197*768 + i] = cls[i] + pos[i];
}

// ---------------- launch ----------------
extern "C" void kernel_launch(void* const* d_in, const int* in_sizes, int n_in,
                              void* d_out, int out_size, void* d_ws, size_t ws_size,
                              hipStream_t stream){
  const float* x      = (const float*)d_in[0];
  const float* W_enc  = (const float*)d_in[1];
  const float* b_enc  = (const float*)d_in[2];
  const float* cls    = (const float*)d_in[3];
  const float* pos    = (const float*)d_in[4];
  const float* gamma  = (const float*)d_in[5];
  const float* bias   = (const float*)d_in[6];
  const float* Wq     = (const float*)d_in[7];
  const float* Wk     = (const float*)d_in[8];
  const float* Whn    = (const float*)d_in[9];
  const float* araw   = (const float*)d_in[10];
  const float* ln_g   = (const float*)d_in[11];
  const float* ln_b   = (const float*)d_in[12];
  const float* W_dec  = (const float*)d_in[13];
  const float* b_dec  = (const float*)d_in[14];
  float* out = (float*)d_out;
  (void)in_sizes; (void)n_in; (void)out_size;

  const int M  = 64*197;   // 12608
  const int MX = 64*196;   // 12544

  // ---- workspace ----
  char* p = (char*)d_ws;
  float* t   = (float*)p;  p += (size_t)M*768*4;        // 38.7 MB
  u16*   g   = (u16*)p;    p += (size_t)M*768*2;        // 19.4 MB (LN out)
  u16*   Qb  = (u16*)p;    p += (size_t)M*768*2;        // 19.4 MB (Gq out; xb overlay)
  u16*   Kb  = (u16*)p;    p += (size_t)M*768*2;        // 19.4 MB (Gk out; WencT/WdecT overlay)
  size_t base = (size_t)(p - (char*)d_ws);
  if(base > ws_size) return;
  // merged-hopfield hidden buffer (77.46 MB) if it fits, else 2-chunk overlay on Qb/Kb
  u16* hidden; int hop_merged;
  if(base + (size_t)M*3072*2 <= ws_size){ hidden = (u16*)(d_ws) + base/2; hop_merged = 1; }
  else { hidden = Qb; hop_merged = 0; }

  // ---- weights live inside d_out (28.3 MB of 38.5 MB; fully dead before decode write) ----
  u16* Wall = (u16*)d_out;
  u16* Wqkb = Wall;               // 2 x [Wq(768 rows); Wk(768 rows)] x 768
  u16* WqkT = Wall + 2359296;     // 2 x 768 x [WqT | WkT] (stride 1536)
  u16* WhnT = Wall + 4718592;     // 2 x 3072 x 768
  u16* WhnB = Wall + 9437184;     // 2 x 768 x 3072 (row-major, ldb 3072)
  u16* xb    = Qb;                // encode-time overlay
  u16* WencT = Kb;                // encode-time overlay
  u16* WdecT = Kb;                // decode-time overlay

  // ---- weight prep ----
  for(int b=0;b<2;b++){
    cvt_k<<<512,256,0,stream>>>(Wq + (size_t)b*589824, Wqkb + (size_t)b*1179648, 589824);
    cvt_k<<<512,256,0,stream>>>(Wk + (size_t)b*589824, Wqkb + (size_t)b*1179648 + 589824, 589824);
    tr_k<<<dim3(24,24),256,0,stream>>>(Wq + (size_t)b*589824, WqkT + (size_t)b*1179648, 768,768, 1536, 0);
    tr_k<<<dim3(24,24),256,0,stream>>>(Wk + (size_t)b*589824, WqkT + (size_t)b*1179648, 768,768, 1536, 768);
    tr_k<<<dim3(96,24),256,0,stream>>>(Whn + (size_t)b*2359296, WhnT + (size_t)b*2359296, 768,3072, 768, 0);
    cvt_k<<<2048,256,0,stream>>>(Whn + (size_t)b*2359296, WhnB + (size_t)b*2359296, 2359296);
  }

  // ---- encode: t = [cls; x@W_enc + b_enc] + pos ----
  cvt_k<<<1024,256,0,stream>>>(x, xb, MX*768);
  tr_k<<<dim3(24,24),256,0,stream>>>(W_enc, WencT, 768,768, 768, 0);
  fill_cls_k<<<64,256,0,stream>>>(t, cls, pos);
  gemm_bt<3,0><<<dim3(6,98),256,0,stream>>>(xb, nullptr, WencT, nullptr, t,
                                            MX, 768, 768, 768, 768,
                                            b_enc, pos, nullptr, 0);

  // ---- energy-descent blocks ----
  for(int blk=0; blk<2; blk++){
    for(int s=0; s<4; s++){
      norm_k<<<M,256,0,stream>>>(t, g, gamma, bias, blk, 0);
      if(hop_merged){
        gemm_bt<1,0><<<dim3(24,99),256,0,stream>>>(g, nullptr,
            WhnT + (size_t)blk*2359296,
            hidden, nullptr, M, 3072, 768, 768, 3072,
            nullptr, nullptr, nullptr, 0);
        gemm_bt<2,0><<<dim3(6,99),256,0,stream>>>(hidden, nullptr,
            WhnB + (size_t)blk*2359296,
            nullptr, t, M, 768, 3072, 3072, 768,
            nullptr, nullptr, araw, blk);
      } else {
        for(int c=0;c<2;c++){
          gemm_bt<1,0><<<dim3(12,99),256,0,stream>>>(g, nullptr,
              WhnT + (size_t)blk*2359296 + (size_t)c*1536*768,
              hidden, nullptr, M, 1536, 768, 768, 1536,
              nullptr, nullptr, nullptr, 0);
          gemm_bt<2,0><<<dim3(6,99),256,0,stream>>>(hidden, nullptr,
              WhnB + (size_t)blk*2359296 + (size_t)c*1536,
              nullptr, t, M, 768, 1536, 3072, 768,
              nullptr, nullptr, araw, blk);
        }
      }
      // fused QK-projection + attention: reads g + Wqk, writes Gq -> Qb, Gk -> Kb
      attn_fused<<<768,256,0,stream>>>(g, Wqkb + (size_t)blk*1179648, Qb, Kb);
      // gradient projection (merged K=1536, split-A: A=Gq(Qb), A2=Gk(Kb))
      gemm_bt<2,1><<<dim3(6,99),256,0,stream>>>(Qb, Kb, WqkT + (size_t)blk*1179648,
            nullptr, t, M, 768, 1536, 1536, 768,
            nullptr, nullptr, araw, blk);
    }
  }

  // ---- decode: LN -> GEMM -> drop CLS ----
  tr_k<<<dim3(24,24),256,0,stream>>>(W_dec, WdecT, 768,768, 768, 0);
  norm_k<<<M,256,0,stream>>>(t, g, ln_g, ln_b, 0, 1);
  gemm_bt<4,0><<<dim3(6,99),256,0,stream>>>(g, nullptr, WdecT, nullptr, out,
                                            M, 768, 768, 768, 768,
                                            b_dec, nullptr, nullptr, 0);
}

// Round 5
// 5180.191 us; speedup vs baseline: 1.0726x; 1.0642x over previous
//
#include <hip/hip_runtime.h>
#include <cstdint>
#include <cstddef>

using u16 = unsigned short;
typedef short short8 __attribute__((ext_vector_type(8)));
typedef short short4v __attribute__((ext_vector_type(4)));
typedef float f32x4 __attribute__((ext_vector_type(4)));

#define LN_EPS 1e-5f
#define ATT_BETA 0.125f

__device__ __forceinline__ u16 f2bf(float f){
  uint32_t u = __float_as_uint(f);
  u += 0x7fffu + ((u >> 16) & 1u);
  return (u16)(u >> 16);
}
__device__ __forceinline__ float bf2f(u16 h){
  return __uint_as_float(((uint32_t)h) << 16);
}
__device__ __forceinline__ float wred_sum(float v){
  #pragma unroll
  for(int o=32;o;o>>=1) v += __shfl_xor(v,o,64);
  return v;
}
__device__ __forceinline__ void async16(const void* g, void* l){
  __builtin_amdgcn_global_load_lds((const __attribute__((address_space(1))) void*)g,
                                   (__attribute__((address_space(3))) void*)l, 16, 0, 0);
}

// ---------------- generic bf16 MFMA GEMM: C[M,N] = A[M,K] * B[N,K]^T (B row stride ldb) -------
// EPI: 1=bf16+relu out (row stride ldc), 2=t += alpha*acc (plain RMW), 3=encode epilogue,
//      4=decode epilogue
// ASPL: A operand split: k<768 from A, k>=768 from A2 (both row stride 768)
template<int EPI, int ASPL>
__global__ __launch_bounds__(256)
void gemm_bt(const u16* __restrict__ A, const u16* __restrict__ A2,
             const u16* __restrict__ B,
             u16* __restrict__ Cb, float* __restrict__ Cf,
             int M, int N, int K, int ldb, int ldc,
             const float* __restrict__ aux0, const float* __restrict__ aux1,
             const float* __restrict__ araw, int blk)
{
  __shared__ u16 lA[128*32];
  __shared__ u16 lB[128*32];
  int tid = threadIdx.x;
  int w = tid >> 6, l = tid & 63;
  int wm = w >> 1, wn = w & 1;
  int m0 = blockIdx.y * 128, n0 = blockIdx.x * 128;
  int lr = l >> 2;           // row within 16-row chunk
  int lc = (l & 3) * 8;      // col (elements) within 32-wide K slab
  f32x4 acc[4][4];
  #pragma unroll
  for(int i=0;i<4;i++)
    #pragma unroll
    for(int j=0;j<4;j++) acc[i][j] = (f32x4){0.f,0.f,0.f,0.f};
  int fm = l & 15, fq = (l >> 4) * 8;

  for(int kt=0; kt<K; kt+=32){
    __syncthreads();
    const u16* Asrc = A; int kcol = kt;
    if(ASPL){ if(kt >= 768){ Asrc = A2; kcol = kt - 768; } }
    int lda = ASPL ? 768 : K;
    #pragma unroll
    for(int c=0;c<2;c++){
      int rr = (w*2+c)*16;
      int ga = m0 + rr + lr; if(ga > M-1) ga = M-1;
      async16(Asrc + (size_t)ga*lda + kcol + lc, &lA[rr*32]);
      int gb = n0 + rr + lr; if(gb > N-1) gb = N-1;
      async16(B + (size_t)gb*ldb + kt + lc, &lB[rr*32]);
    }
    __syncthreads();
    short8 af[4], bfv[4];
    #pragma unroll
    for(int i=0;i<4;i++) af[i]  = *(const short8*)&lA[(wm*64 + i*16 + fm)*32 + fq];
    #pragma unroll
    for(int j=0;j<4;j++) bfv[j] = *(const short8*)&lB[(wn*64 + j*16 + fm)*32 + fq];
    #pragma unroll
    for(int i=0;i<4;i++)
      #pragma unroll
      for(int j=0;j<4;j++)
        acc[i][j] = __builtin_amdgcn_mfma_f32_16x16x32_bf16(af[i], bfv[j], acc[i][j], 0, 0, 0);
  }

  float alpha = 0.f;
  if(EPI==2) alpha = log1pf(__expf(araw[blk]));

  #pragma unroll
  for(int i=0;i<4;i++){
    int row_b = m0 + wm*64 + i*16 + (l>>4)*4;
    #pragma unroll
    for(int j=0;j<4;j++){
      int col = n0 + wn*64 + j*16 + (l&15);
      #pragma unroll
      for(int r=0;r<4;r++){
        int row = row_b + r;
        if(row >= M) continue;
        float v = acc[i][j][r];
        if(EPI==1){
          Cb[(size_t)row*ldc + col] = f2bf(v > 0.f ? v : 0.f);
        } else if(EPI==2){
          Cf[(size_t)row*768 + col] += alpha * v;
        } else if(EPI==3){
          int pb = row / 196, pn = row - pb*196;
          Cf[((size_t)pb*197 + 1 + pn)*768 + col] = v + aux0[col] + aux1[(size_t)(1+pn)*768 + col];
        } else { // EPI==4
          int pb = row / 197, rr2 = row - pb*197;
          if(rr2 > 0) Cf[((size_t)pb*196 + rr2 - 1)*768 + col] = v + aux0[col];
        }
      }
    }
  }
}

// ---------------- LN: mode 0 = EnergyLN (scalar gamma + per-dim bias), 1 = final LN ----------
// vectorized: 192 threads x f32x4 loads (768 = 192*4)
__global__ __launch_bounds__(256)
void norm_k(const float* __restrict__ t, u16* __restrict__ out,
            const float* __restrict__ gv, const float* __restrict__ bv, int blk, int mode)
{
  __shared__ float r1[4], r2[4];
  int row = blockIdx.x;
  const float* tr = t + (size_t)row*768;
  int tid = threadIdx.x, w = tid>>6, l = tid&63;
  f32x4 v = (f32x4){0.f,0.f,0.f,0.f};
  float s=0.f, s2=0.f;
  if(tid < 192){
    v = ((const f32x4*)tr)[tid];
    s  = v[0]+v[1]+v[2]+v[3];
    s2 = v[0]*v[0]+v[1]*v[1]+v[2]*v[2]+v[3]*v[3];
  }
  s = wred_sum(s); s2 = wred_sum(s2);
  if(l==0){ r1[w]=s; r2[w]=s2; }
  __syncthreads();
  s  = r1[0]+r1[1]+r1[2]+r1[3];
  s2 = r2[0]+r2[1]+r2[2]+r2[3];
  float mu  = s * (1.0f/768.0f);
  float var = s2 * (1.0f/768.0f) - mu*mu;
  float rs  = rsqrtf(var + LN_EPS);
  u16* orow = out + (size_t)row*768;
  if(tid < 192){
    short4v o;
    if(mode==0){
      float gm = gv[blk];
      const float* bb = bv + blk*768;
      #pragma unroll
      for(int c=0;c<4;c++) o[c] = (short)f2bf((v[c]-mu)*rs*gm + bb[tid*4+c]);
    } else {
      #pragma unroll
      for(int c=0;c<4;c++) o[c] = (short)f2bf((v[c]-mu)*rs*gv[tid*4+c] + bv[tid*4+c]);
    }
    ((short4v*)orow)[tid] = o;
  }
}

// ---------------- fused QK-projection + attention per (b,h), 8 waves --------------------------
// Grid 768 x 512 threads. Phase A: Q = g Wq^T, K = g Wk^T via MFMA; outputs written to LDS in
// BOTH row-major ([208][72]) and transposed ([64][232]) layouts straight from accumulators.
// Phase B: attention body (scores -> no-max softmax -> Gq = P K, Gk += P^T Q over stripes),
// all Q/K/QT/KT reads from LDS. 8 waves = 2/SIMD for latency hiding (R4 had 1/SIMD -> 378us).
__global__ __launch_bounds__(512)
void attn_fused(const u16* __restrict__ g, const u16* __restrict__ Wqk,
                u16* __restrict__ GqO, u16* __restrict__ GkO)
{
  __shared__ u16 Qlds[208*72];   // 29,952 B  row q stride 72 (144B, 16B-aligned)
  __shared__ u16 Klds[208*72];   // 29,952 B
  __shared__ u16 QTl[64*232];    // 29,696 B  row z stride 232 (464B, 16B-aligned)
  __shared__ u16 KTl[64*232];    // 29,696 B
  __shared__ u16 P[32*256];      // 16,384 B  swizzled row-major P
  __shared__ u16 PT[224*40];     // 17,920 B
  __shared__ float SredS[2][4][16];
  // total ~154 KB < 160 KiB -> 1 block/CU, 8 waves

  int bhw = blockIdx.x;
  int bh = (bhw & 7)*96 + (bhw >> 3);   // bijective XCD chunk swizzle (768 % 8 == 0)
  int b = bh/12, h = bh - b*12;
  const u16* grows = g + (size_t)b*197*768;
  u16* Qg = GqO + (size_t)b*197*768 + h*64;
  u16* Kg = GkO + (size_t)b*197*768 + h*64;
  int tid = threadIdx.x, w = tid>>6, l = tid&63;
  int lane16 = l & 15, quad = l >> 4;

  // zero transposed-pad cols 208..231 (read by Gq kt=6 / Gk st=6 upper quads)
  for(int idx=tid; idx<64*24; idx+=512){
    int z = idx/24, c = 208 + (idx - (idx/24)*24);
    QTl[z*232 + c] = 0; KTl[z*232 + c] = 0;
  }

  // ---- phase A: projection. waves 0-3 -> Q (z-tile w&3); waves 4-7 -> K.
  {
    int half = w >> 2;            // 0=Q, 1=K
    int nt   = w & 3;             // one 16-col z-tile per wave
    const u16* Wb = Wqk + (size_t)half*589824 + (size_t)(h*64)*768;
    u16* Lr = half ? Klds : Qlds;
    u16* Lt = half ? KTl  : QTl;
    f32x4 acc[13];
    #pragma unroll
    for(int rt=0;rt<13;rt++) acc[rt]=(f32x4){0.f,0.f,0.f,0.f};
    for(int kt=0; kt<24; kt++){
      int ko = kt*32 + quad*8;
      short8 b0 = *(const short8*)(Wb + (size_t)(nt*16 + lane16)*768 + ko);
      #pragma unroll
      for(int rt=0; rt<13; rt++){
        int gr = rt*16 + lane16; if(gr > 196) gr = 196;
        short8 af = *(const short8*)(grows + (size_t)gr*768 + ko);
        acc[rt] = __builtin_amdgcn_mfma_f32_16x16x32_bf16(af, b0, acc[rt],0,0,0);
      }
    }
    #pragma unroll
    for(int rt=0; rt<13; rt++)
      #pragma unroll
      for(int r=0; r<4; r++){
        int q = rt*16 + quad*4 + r;       // D-layout: row=(l>>4)*4+r
        int z = nt*16 + lane16;           //           col=l&15
        u16 hv = f2bf(acc[rt][r]);
        Lr[q*72  + z] = hv;
        Lt[z*232 + q] = hv;
      }
  }
  __syncthreads();

  // ---- phase B: attention body, LDS-sourced, 8-wave split
  int mt = w & 1, nh = w >> 1;                  // mt: q-half of stripe; nh: 0..3
  int ncnt = (nh==0) ? 4 : 3;                   // score n-tiles: {4,3,3,3} over 13
  int nt0s = (nh==0) ? 0 : (1 + 3*nh);
  int jt0 = (w<5) ? 2*w : 10+(w-5);             // Gk j-tiles: {2,2,2,2,2,1,1,1}
  int jn  = (w<5) ? 2 : 1;

  f32x4 gk[2][4];
  #pragma unroll
  for(int a=0;a<2;a++)
    #pragma unroll
    for(int n2=0;n2<4;n2++) gk[a][n2] = (f32x4){0.f,0.f,0.f,0.f};

  for(int st=0; st<7; st++){
    int q0 = st*32;
    __syncthreads();   // protect P/PT/SredS rewrite vs previous stripe readers
    int qa = q0 + 16*mt + lane16; if(qa > 196) qa = 196;
    short8 a0 = *(const short8*)&Qlds[qa*72 + quad*8];
    short8 a1 = *(const short8*)&Qlds[qa*72 + 32 + quad*8];
    f32x4 sa[4];
    #pragma unroll
    for(int ni=0;ni<4;ni++) sa[ni] = (f32x4){0.f,0.f,0.f,0.f};
    for(int ni=0; ni<ncnt; ni++){
      int jb = (nt0s+ni)*16 + lane16; if(jb > 196) jb = 196;
      short8 b0 = *(const short8*)&Klds[jb*72 + quad*8];
      short8 b1 = *(const short8*)&Klds[jb*72 + 32 + quad*8];
      sa[ni] = __builtin_amdgcn_mfma_f32_16x16x32_bf16(a0, b0, sa[ni],0,0,0);
      sa[ni] = __builtin_amdgcn_mfma_f32_16x16x32_bf16(a1, b1, sa[ni],0,0,0);
    }
    for(int ni=0; ni<ncnt; ni++){
      if((nt0s+ni)*16 + lane16 > 196){
        sa[ni][0]=-3e38f; sa[ni][1]=-3e38f; sa[ni][2]=-3e38f; sa[ni][3]=-3e38f;
      }
    }
    // no-max softmax (beta=0.125, logits bounded; arg clamped)
    float ss[4] = {0.f,0.f,0.f,0.f};
    for(int ni=0; ni<ncnt; ni++)
      #pragma unroll
      for(int r=0;r<4;r++){
        float e = __expf(fminf(ATT_BETA*sa[ni][r], 80.f));
        sa[ni][r] = e; ss[r] += e;
      }
    #pragma unroll
    for(int o=1;o<16;o<<=1)
      #pragma unroll
      for(int r=0;r<4;r++) ss[r] += __shfl_xor(ss[r], o, 64);
    if(lane16==0){
      #pragma unroll
      for(int r=0;r<4;r++) SredS[mt][nh][quad*4+r] = ss[r];
    }
    __syncthreads();
    float inv[4];
    #pragma unroll
    for(int r=0;r<4;r++)
      inv[r] = 1.f/(SredS[mt][0][quad*4+r] + SredS[mt][1][quad*4+r]
                  + SredS[mt][2][quad*4+r] + SredS[mt][3][quad*4+r]);
    // write P (swizzled) + PT (packed b64); rows q>196 forced 0
    for(int ni=0; ni<ncnt; ni++){
      int j = (nt0s+ni)*16 + lane16;
      short4v pk;
      #pragma unroll
      for(int r=0;r<4;r++){
        int q = 16*mt + quad*4 + r;
        float val = (q0 + q <= 196) ? sa[ni][r]*inv[r] : 0.f;
        u16 hv = f2bf(val);
        P[q*256 + 8*((j>>3)^(q&7)) + (j&7)] = hv;
        pk[r] = (short)hv;
      }
      *(short4v*)&PT[j*40 + 16*mt + 4*quad] = pk;
    }
    // zero P logical cols 208..223 (read by Gq kt=6 upper quads)
    for(int idx=tid; idx<32*16; idx+=512){
      int q = idx>>4, j = 208 + (idx&15);
      P[q*256 + 8*((j>>3)^(q&7)) + (j&7)] = 0;
    }
    __syncthreads();
    // ---- Gq = P K : one 16x16 tile per wave (mt x nh), B-frags from KTl
    {
      f32x4 gq = (f32x4){0.f,0.f,0.f,0.f};
      int qrow = 16*mt + lane16;
      int z = nh*16 + lane16;
      for(int kt=0; kt<7; kt++){
        short8 af = *(const short8*)&P[qrow*256 + 8*((4*kt+quad)^(qrow&7))];
        short8 bf8 = *(const short8*)&KTl[z*232 + kt*32 + quad*8];
        gq = __builtin_amdgcn_mfma_f32_16x16x32_bf16(af, bf8, gq,0,0,0);
      }
      #pragma unroll
      for(int r=0;r<4;r++){
        int qg2 = q0 + 16*mt + quad*4 + r;
        if(qg2 <= 196) Qg[(size_t)qg2*768 + nh*16 + lane16] = f2bf(gq[r]);
      }
    }
    // ---- Gk accumulate: A-frags from PT, B-frags from QTl
    {
      short8 bq[4];
      #pragma unroll
      for(int n2=0;n2<4;n2++)
        bq[n2] = *(const short8*)&QTl[(n2*16+lane16)*232 + q0 + quad*8];
      for(int ji=0; ji<jn; ji++){
        int j = (jt0+ji)*16 + lane16;
        short8 af = *(const short8*)&PT[j*40 + quad*8];
        #pragma unroll
        for(int n2=0;n2<4;n2++)
          gk[ji][n2] = __builtin_amdgcn_mfma_f32_16x16x32_bf16(af, bq[n2], gk[ji][n2],0,0,0);
      }
    }
  }
  __syncthreads();
  for(int ji=0; ji<jn; ji++){
    int jt = jt0 + ji;
    #pragma unroll
    for(int n2=0;n2<4;n2++)
      #pragma unroll
      for(int r=0;r<4;r++){
        int j = jt*16 + quad*4 + r;
        if(j <= 196) Kg[(size_t)j*768 + n2*16 + lane16] = f2bf(gk[ji][n2][r]);
      }
  }
}

// ---------------- small utility kernels ----------------
__global__ void cvt_k(const float* __restrict__ in, u16* __restrict__ out, int n){
  for(int i=blockIdx.x*256+threadIdx.x; i<n; i+=gridDim.x*256) out[i] = f2bf(in[i]);
}

// dst[c*dstride + coff + r] = bf16(src[r*C + c]); R,C multiples of 32
__global__ __launch_bounds__(256)
void tr_k(const float* __restrict__ src, u16* __restrict__ dst, int R, int C, int dstride, int coff){
  __shared__ float tile[32][33];
  int c0 = blockIdx.x*32, r0 = blockIdx.y*32;
  int tx = threadIdx.x & 31, ty = threadIdx.x >> 5;
  for(int i=ty;i<32;i+=8) tile[i][tx] = src[(size_t)(r0+i)*C + c0 + tx];
  __syncthreads();
  for(int i=ty;i<32;i+=8) dst[(size_t)(c0+i)*dstride + coff + r0 + tx] = f2bf(tile[tx][i]);
}

__global__ void fill_cls_k(float* __restrict__ t, const float* __restrict__ cls, const float* __restrict__ pos){
  int b = blockIdx.x;
  for(int i=threadIdx.x;i<768;i+=256) t[(size_t)b*197*768 + i] = cls[i] + pos[i];
}

// ---------------- launch ----------------
extern "C" void kernel_launch(void* const* d_in, const int* in_sizes, int n_in,
                              void* d_out, int out_size, void* d_ws, size_t ws_size,
                              hipStream_t stream){
  const float* x      = (const float*)d_in[0];
  const float* W_enc  = (const float*)d_in[1];
  const float* b_enc  = (const float*)d_in[2];
  const float* cls    = (const float*)d_in[3];
  const float* pos    = (const float*)d_in[4];
  const float* gamma  = (const float*)d_in[5];
  const float* bias   = (const float*)d_in[6];
  const float* Wq     = (const float*)d_in[7];
  const float* Wk     = (const float*)d_in[8];
  const float* Whn    = (const float*)d_in[9];
  const float* araw   = (const float*)d_in[10];
  const float* ln_g   = (const float*)d_in[11];
  const float* ln_b   = (const float*)d_in[12];
  const float* W_dec  = (const float*)d_in[13];
  const float* b_dec  = (const float*)d_in[14];
  float* out = (float*)d_out;
  (void)in_sizes; (void)n_in; (void)out_size;

  const int M  = 64*197;   // 12608
  const int MX = 64*196;   // 12544

  // ---- workspace ----
  char* p = (char*)d_ws;
  float* t   = (float*)p;  p += (size_t)M*768*4;        // 38.7 MB
  u16*   g   = (u16*)p;    p += (size_t)M*768*2;        // 19.4 MB (LN out)
  u16*   Qb  = (u16*)p;    p += (size_t)M*768*2;        // 19.4 MB (Gq out; xb overlay)
  u16*   Kb  = (u16*)p;    p += (size_t)M*768*2;        // 19.4 MB (Gk out; WencT/WdecT overlay)
  size_t base = (size_t)(p - (char*)d_ws);
  if(base > ws_size) return;
  // merged-hopfield hidden buffer (77.46 MB) if it fits, else 2-chunk overlay on Qb/Kb
  u16* hidden; int hop_merged;
  if(base + (size_t)M*3072*2 <= ws_size){ hidden = (u16*)(d_ws) + base/2; hop_merged = 1; }
  else { hidden = Qb; hop_merged = 0; }

  // ---- weights live inside d_out (28.3 MB of 38.5 MB; fully dead before decode write) ----
  u16* Wall = (u16*)d_out;
  u16* Wqkb = Wall;               // 2 x [Wq(768 rows); Wk(768 rows)] x 768
  u16* WqkT = Wall + 2359296;     // 2 x 768 x [WqT | WkT] (stride 1536)
  u16* WhnT = Wall + 4718592;     // 2 x 3072 x 768
  u16* WhnB = Wall + 9437184;     // 2 x 768 x 3072 (row-major, ldb 3072)
  u16* xb    = Qb;                // encode-time overlay
  u16* WencT = Kb;                // encode-time overlay
  u16* WdecT = Kb;                // decode-time overlay

  // ---- weight prep ----
  for(int b=0;b<2;b++){
    cvt_k<<<512,256,0,stream>>>(Wq + (size_t)b*589824, Wqkb + (size_t)b*1179648, 589824);
    cvt_k<<<512,256,0,stream>>>(Wk + (size_t)b*589824, Wqkb + (size_t)b*1179648 + 589824, 589824);
    tr_k<<<dim3(24,24),256,0,stream>>>(Wq + (size_t)b*589824, WqkT + (size_t)b*1179648, 768,768, 1536, 0);
    tr_k<<<dim3(24,24),256,0,stream>>>(Wk + (size_t)b*589824, WqkT + (size_t)b*1179648, 768,768, 1536, 768);
    tr_k<<<dim3(96,24),256,0,stream>>>(Whn + (size_t)b*2359296, WhnT + (size_t)b*2359296, 768,3072, 768, 0);
    cvt_k<<<2048,256,0,stream>>>(Whn + (size_t)b*2359296, WhnB + (size_t)b*2359296, 2359296);
  }

  // ---- encode: t = [cls; x@W_enc + b_enc] + pos ----
  cvt_k<<<1024,256,0,stream>>>(x, xb, MX*768);
  tr_k<<<dim3(24,24),256,0,stream>>>(W_enc, WencT, 768,768, 768, 0);
  fill_cls_k<<<64,256,0,stream>>>(t, cls, pos);
  gemm_bt<3,0><<<dim3(6,98),256,0,stream>>>(xb, nullptr, WencT, nullptr, t,
                                            MX, 768, 768, 768, 768,
                                            b_enc, pos, nullptr, 0);

  // ---- energy-descent blocks ----
  for(int blk=0; blk<2; blk++){
    for(int s=0; s<4; s++){
      norm_k<<<M,256,0,stream>>>(t, g, gamma, bias, blk, 0);
      if(hop_merged){
        gemm_bt<1,0><<<dim3(24,99),256,0,stream>>>(g, nullptr,
            WhnT + (size_t)blk*2359296,
            hidden, nullptr, M, 3072, 768, 768, 3072,
            nullptr, nullptr, nullptr, 0);
        gemm_bt<2,0><<<dim3(6,99),256,0,stream>>>(hidden, nullptr,
            WhnB + (size_t)blk*2359296,
            nullptr, t, M, 768, 3072, 3072, 768,
            nullptr, nullptr, araw, blk);
      } else {
        for(int c=0;c<2;c++){
          gemm_bt<1,0><<<dim3(12,99),256,0,stream>>>(g, nullptr,
              WhnT + (size_t)blk*2359296 + (size_t)c*1536*768,
              hidden, nullptr, M, 1536, 768, 768, 1536,
              nullptr, nullptr, nullptr, 0);
          gemm_bt<2,0><<<dim3(6,99),256,0,stream>>>(hidden, nullptr,
              WhnB + (size_t)blk*2359296 + (size_t)c*1536,
              nullptr, t, M, 768, 1536, 3072, 768,
              nullptr, nullptr, araw, blk);
        }
      }
      // fused QK-projection + attention: reads g + Wqk, writes Gq -> Qb, Gk -> Kb
      attn_fused<<<768,512,0,stream>>>(g, Wqkb + (size_t)blk*1179648, Qb, Kb);
      // gradient projection (merged K=1536, split-A: A=Gq(Qb), A2=Gk(Kb))
      gemm_bt<2,1><<<dim3(6,99),256,0,stream>>>(Qb, Kb, WqkT + (size_t)blk*1179648,
            nullptr, t, M, 768, 1536, 1536, 768,
            nullptr, nullptr, araw, blk);
    }
  }

  // ---- decode: LN -> GEMM -> drop CLS ----
  tr_k<<<dim3(24,24),256,0,stream>>>(W_dec, WdecT, 768,768, 768, 0);
  norm_k<<<M,256,0,stream>>>(t, g, ln_g, ln_b, 0, 1);
  gemm_bt<4,0><<<dim3(6,99),256,0,stream>>>(g, nullptr, WdecT, nullptr, out,
                                            M, 768, 768, 768, 768,
                                            b_dec, nullptr, nullptr, 0);
}

// Round 6
// 4211.334 us; speedup vs baseline: 1.3194x; 1.2301x over previous
//
#include <hip/hip_runtime.h>
#include <cstdint>
#include <cstddef>

using u16 = unsigned short;
typedef short short8 __attribute__((ext_vector_type(8)));
typedef short short4v __attribute__((ext_vector_type(4)));
typedef float f32x4 __attribute__((ext_vector_type(4)));

#define LN_EPS 1e-5f
#define ATT_BETA 0.125f

__device__ __forceinline__ u16 f2bf(float f){
  uint32_t u = __float_as_uint(f);
  u += 0x7fffu + ((u >> 16) & 1u);
  return (u16)(u >> 16);
}
__device__ __forceinline__ float bf2f(u16 h){
  return __uint_as_float(((uint32_t)h) << 16);
}
__device__ __forceinline__ float wred_sum(float v){
  #pragma unroll
  for(int o=32;o;o>>=1) v += __shfl_xor(v,o,64);
  return v;
}
__device__ __forceinline__ void async16(const void* g, void* l){
  __builtin_amdgcn_global_load_lds((const __attribute__((address_space(1))) void*)g,
                                   (__attribute__((address_space(3))) void*)l, 16, 0, 0);
}

// ---------------- generic bf16 MFMA GEMM: C[M,N] = A[M,K] * B[N,K]^T (B row stride ldb) -------
// EPI: 1=bf16+relu out (row stride ldc), 2=t += alpha*acc (plain RMW), 3=encode epilogue,
//      4=decode epilogue
// ASPL: A operand split: k<768 from A, k>=768 from A2 (both row stride 768)
template<int EPI, int ASPL>
__global__ __launch_bounds__(256)
void gemm_bt(const u16* __restrict__ A, const u16* __restrict__ A2,
             const u16* __restrict__ B,
             u16* __restrict__ Cb, float* __restrict__ Cf,
             int M, int N, int K, int ldb, int ldc,
             const float* __restrict__ aux0, const float* __restrict__ aux1,
             const float* __restrict__ araw, int blk)
{
  __shared__ u16 lA[128*32];
  __shared__ u16 lB[128*32];
  int tid = threadIdx.x;
  int w = tid >> 6, l = tid & 63;
  int wm = w >> 1, wn = w & 1;
  int m0 = blockIdx.y * 128, n0 = blockIdx.x * 128;
  int lr = l >> 2;           // row within 16-row chunk
  int lc = (l & 3) * 8;      // col (elements) within 32-wide K slab
  f32x4 acc[4][4];
  #pragma unroll
  for(int i=0;i<4;i++)
    #pragma unroll
    for(int j=0;j<4;j++) acc[i][j] = (f32x4){0.f,0.f,0.f,0.f};
  int fm = l & 15, fq = (l >> 4) * 8;

  for(int kt=0; kt<K; kt+=32){
    __syncthreads();
    const u16* Asrc = A; int kcol = kt;
    if(ASPL){ if(kt >= 768){ Asrc = A2; kcol = kt - 768; } }
    int lda = ASPL ? 768 : K;
    #pragma unroll
    for(int c=0;c<2;c++){
      int rr = (w*2+c)*16;
      int ga = m0 + rr + lr; if(ga > M-1) ga = M-1;
      async16(Asrc + (size_t)ga*lda + kcol + lc, &lA[rr*32]);
      int gb = n0 + rr + lr; if(gb > N-1) gb = N-1;
      async16(B + (size_t)gb*ldb + kt + lc, &lB[rr*32]);
    }
    __syncthreads();
    short8 af[4], bfv[4];
    #pragma unroll
    for(int i=0;i<4;i++) af[i]  = *(const short8*)&lA[(wm*64 + i*16 + fm)*32 + fq];
    #pragma unroll
    for(int j=0;j<4;j++) bfv[j] = *(const short8*)&lB[(wn*64 + j*16 + fm)*32 + fq];
    #pragma unroll
    for(int i=0;i<4;i++)
      #pragma unroll
      for(int j=0;j<4;j++)
        acc[i][j] = __builtin_amdgcn_mfma_f32_16x16x32_bf16(af[i], bfv[j], acc[i][j], 0, 0, 0);
  }

  float alpha = 0.f;
  if(EPI==2) alpha = log1pf(__expf(araw[blk]));

  #pragma unroll
  for(int i=0;i<4;i++){
    int row_b = m0 + wm*64 + i*16 + (l>>4)*4;
    #pragma unroll
    for(int j=0;j<4;j++){
      int col = n0 + wn*64 + j*16 + (l&15);
      #pragma unroll
      for(int r=0;r<4;r++){
        int row = row_b + r;
        if(row >= M) continue;
        float v = acc[i][j][r];
        if(EPI==1){
          Cb[(size_t)row*ldc + col] = f2bf(v > 0.f ? v : 0.f);
        } else if(EPI==2){
          Cf[(size_t)row*768 + col] += alpha * v;
        } else if(EPI==3){
          int pb = row / 196, pn = row - pb*196;
          Cf[((size_t)pb*197 + 1 + pn)*768 + col] = v + aux0[col] + aux1[(size_t)(1+pn)*768 + col];
        } else { // EPI==4
          int pb = row / 197, rr2 = row - pb*197;
          if(rr2 > 0) Cf[((size_t)pb*196 + rr2 - 1)*768 + col] = v + aux0[col];
        }
      }
    }
  }
}

// ---------------- LN: mode 0 = EnergyLN (scalar gamma + per-dim bias), 1 = final LN ----------
// vectorized: 192 threads x f32x4 loads (768 = 192*4)
__global__ __launch_bounds__(256)
void norm_k(const float* __restrict__ t, u16* __restrict__ out,
            const float* __restrict__ gv, const float* __restrict__ bv, int blk, int mode)
{
  __shared__ float r1[4], r2[4];
  int row = blockIdx.x;
  const float* tr = t + (size_t)row*768;
  int tid = threadIdx.x, w = tid>>6, l = tid&63;
  f32x4 v = (f32x4){0.f,0.f,0.f,0.f};
  float s=0.f, s2=0.f;
  if(tid < 192){
    v = ((const f32x4*)tr)[tid];
    s  = v[0]+v[1]+v[2]+v[3];
    s2 = v[0]*v[0]+v[1]*v[1]+v[2]*v[2]+v[3]*v[3];
  }
  s = wred_sum(s); s2 = wred_sum(s2);
  if(l==0){ r1[w]=s; r2[w]=s2; }
  __syncthreads();
  s  = r1[0]+r1[1]+r1[2]+r1[3];
  s2 = r2[0]+r2[1]+r2[2]+r2[3];
  float mu  = s * (1.0f/768.0f);
  float var = s2 * (1.0f/768.0f) - mu*mu;
  float rs  = rsqrtf(var + LN_EPS);
  u16* orow = out + (size_t)row*768;
  if(tid < 192){
    short4v o;
    if(mode==0){
      float gm = gv[blk];
      const float* bb = bv + blk*768;
      #pragma unroll
      for(int c=0;c<4;c++) o[c] = (short)f2bf((v[c]-mu)*rs*gm + bb[tid*4+c]);
    } else {
      #pragma unroll
      for(int c=0;c<4;c++) o[c] = (short)f2bf((v[c]-mu)*rs*gv[tid*4+c] + bv[tid*4+c]);
    }
    ((short4v*)orow)[tid] = o;
  }
}

// ---------------- fused QK-projection + attention per (b,h), 8 waves --------------------------
// Grid 768 x 512 threads, __launch_bounds__(512,2) (2 waves/SIMD is the LDS-capped occupancy;
// free the VGPR budget to 256 so the compiler can pipeline).
// Phase A (GEMM-anatomy): g slabs [208][32] double-buffered in LDS via global_load_lds (aliased
// on the P/PT region, dead in phase A); wave = (half Q/K) x (rt row-group); 4 weight B-frags
// held in registers with next-kt prefetch -> 16 MFMA per 4 ds_reads. Outputs written to LDS in
// row-major ([208][72]) and transposed ([64][232]) layouts straight from accumulators.
// Phase B: attention body (scores -> no-max softmax -> Gq = P K, Gk += P^T Q over stripes),
// all Q/K/QT/KT reads from LDS.
__global__ __launch_bounds__(512, 2)
void attn_fused(const u16* __restrict__ g, const u16* __restrict__ Wqk,
                u16* __restrict__ GqO, u16* __restrict__ GkO)
{
  __shared__ u16 smem[76800];          // 153,600 B
  __shared__ float SredS[2][4][16];
  u16* Qlds = smem;                    // [208][72]  29,952 B
  u16* Klds = smem + 14976;            // [208][72]
  u16* QTl  = smem + 29952;            // [64][232]  29,696 B
  u16* KTl  = smem + 44800;            // [64][232]
  u16* P    = smem + 59648;            // [32][256]  16,384 B (phase B)
  u16* PT   = smem + 67840;            // [224][40]  17,920 B (phase B)
  u16* lg   = smem + 59648;            // phase-A alias: [2][208*32] = 26,624 B <= P+PT region

  int bhw = blockIdx.x;
  int bh = (bhw & 7)*96 + (bhw >> 3);   // bijective XCD chunk swizzle (768 % 8 == 0)
  int b = bh/12, h = bh - b*12;
  const u16* grows = g + (size_t)b*197*768;
  u16* Qg = GqO + (size_t)b*197*768 + h*64;
  u16* Kg = GkO + (size_t)b*197*768 + h*64;
  int tid = threadIdx.x, w = tid>>6, l = tid&63;
  int lane16 = l & 15, quad = l >> 4;

  // zero transposed-pad cols 208..231 (read by Gq kt=6 / Gk st=6 upper quads)
  for(int idx=tid; idx<64*24; idx+=512){
    int z = idx/24, c = 208 + (idx - (idx/24)*24);
    QTl[z*232 + c] = 0; KTl[z*232 + c] = 0;
  }

  // ---- phase A: projection, staged. ----
  {
    int half = w >> 2;                   // 0=Q, 1=K
    int wsub = w & 3;                    // rt row-group
    int rt0 = (wsub==0) ? 0 : 1 + 3*wsub;
    int rtn = (wsub==0) ? 4 : 3;
    const u16* Wb = Wqk + (size_t)half*589824 + (size_t)(h*64)*768;
    u16* Lr = half ? Klds : Qlds;
    u16* Lt = half ? KTl  : QTl;
    f32x4 acc[4][4];
    #pragma unroll
    for(int i=0;i<4;i++)
      #pragma unroll
      for(int z=0;z<4;z++) acc[i][z] = (f32x4){0.f,0.f,0.f,0.f};

    // slab staging: 208 rows x 32 cols bf16 = 832 16B-chunks; chunk idx -> (row=idx>>2, c4=idx&3)
    #define STAGE_G(bufi, ktv) do{                                                   \
      int idx0 = tid;                                                                \
      { int rw = idx0>>2, c4 = idx0&3; int r2 = rw>196?196:rw;                       \
        async16(grows + (size_t)r2*768 + (ktv)*32 + c4*8, lg + (bufi)*6656 + idx0*8);}\
      int idx1 = tid + 512;                                                          \
      if(idx1 < 832){ int rw = idx1>>2, c4 = idx1&3; int r2 = rw>196?196:rw;         \
        async16(grows + (size_t)r2*768 + (ktv)*32 + c4*8, lg + (bufi)*6656 + idx1*8);}\
    }while(0)

    short8 bq[4], bqn[4];
    #pragma unroll
    for(int z=0;z<4;z++) bq[z] = *(const short8*)(Wb + (size_t)(z*16+lane16)*768 + quad*8);
    STAGE_G(0, 0);
    int buf = 0;
    for(int kt=0; kt<24; kt++){
      __syncthreads();                  // drains vmcnt -> slab[buf] ready
      if(kt < 23){
        STAGE_G(buf^1, kt+1);
        #pragma unroll
        for(int z=0;z<4;z++)
          bqn[z] = *(const short8*)(Wb + (size_t)(z*16+lane16)*768 + (kt+1)*32 + quad*8);
      }
      const u16* lb = lg + buf*6656;
      #pragma unroll
      for(int i=0;i<4;i++) if(i<rtn){
        short8 af = *(const short8*)(lb + (size_t)((rt0+i)*16 + lane16)*32 + quad*8);
        #pragma unroll
        for(int z=0;z<4;z++)
          acc[i][z] = __builtin_amdgcn_mfma_f32_16x16x32_bf16(af, bq[z], acc[i][z],0,0,0);
      }
      #pragma unroll
      for(int z=0;z<4;z++) bq[z] = bqn[z];
      buf ^= 1;
    }
    #undef STAGE_G

    #pragma unroll
    for(int i=0;i<4;i++) if(i<rtn)
      #pragma unroll
      for(int z=0;z<4;z++)
        #pragma unroll
        for(int r=0;r<4;r++){
          int q  = (rt0+i)*16 + quad*4 + r;   // D-layout: row=(l>>4)*4+r
          int zz = z*16 + lane16;             //           col=l&15
          u16 hv = f2bf(acc[i][z][r]);
          Lr[q*72   + zz] = hv;
          Lt[zz*232 + q ] = hv;
        }
  }
  __syncthreads();

  // ---- phase B: attention body, LDS-sourced, 8-wave split
  int mt = w & 1, nh = w >> 1;                  // mt: q-half of stripe; nh: 0..3
  int ncnt = (nh==0) ? 4 : 3;                   // score n-tiles: {4,3,3,3} over 13
  int nt0s = (nh==0) ? 0 : (1 + 3*nh);
  int jt0 = (w<5) ? 2*w : 10+(w-5);             // Gk j-tiles: {2,2,2,2,2,1,1,1}
  int jn  = (w<5) ? 2 : 1;

  f32x4 gk[2][4];
  #pragma unroll
  for(int a=0;a<2;a++)
    #pragma unroll
    for(int n2=0;n2<4;n2++) gk[a][n2] = (f32x4){0.f,0.f,0.f,0.f};

  for(int st=0; st<7; st++){
    int q0 = st*32;
    __syncthreads();   // protect P/PT/SredS rewrite vs previous stripe readers
    int qa = q0 + 16*mt + lane16; if(qa > 196) qa = 196;
    short8 a0 = *(const short8*)&Qlds[qa*72 + quad*8];
    short8 a1 = *(const short8*)&Qlds[qa*72 + 32 + quad*8];
    f32x4 sa[4];
    #pragma unroll
    for(int ni=0;ni<4;ni++) sa[ni] = (f32x4){0.f,0.f,0.f,0.f};
    for(int ni=0; ni<ncnt; ni++){
      int jb = (nt0s+ni)*16 + lane16; if(jb > 196) jb = 196;
      short8 b0 = *(const short8*)&Klds[jb*72 + quad*8];
      short8 b1 = *(const short8*)&Klds[jb*72 + 32 + quad*8];
      sa[ni] = __builtin_amdgcn_mfma_f32_16x16x32_bf16(a0, b0, sa[ni],0,0,0);
      sa[ni] = __builtin_amdgcn_mfma_f32_16x16x32_bf16(a1, b1, sa[ni],0,0,0);
    }
    for(int ni=0; ni<ncnt; ni++){
      if((nt0s+ni)*16 + lane16 > 196){
        sa[ni][0]=-3e38f; sa[ni][1]=-3e38f; sa[ni][2]=-3e38f; sa[ni][3]=-3e38f;
      }
    }
    // no-max softmax (beta=0.125, logits bounded; arg clamped)
    float ss[4] = {0.f,0.f,0.f,0.f};
    for(int ni=0; ni<ncnt; ni++)
      #pragma unroll
      for(int r=0;r<4;r++){
        float e = __expf(fminf(ATT_BETA*sa[ni][r], 80.f));
        sa[ni][r] = e; ss[r] += e;
      }
    #pragma unroll
    for(int o=1;o<16;o<<=1)
      #pragma unroll
      for(int r=0;r<4;r++) ss[r] += __shfl_xor(ss[r], o, 64);
    if(lane16==0){
      #pragma unroll
      for(int r=0;r<4;r++) SredS[mt][nh][quad*4+r] = ss[r];
    }
    __syncthreads();
    float inv[4];
    #pragma unroll
    for(int r=0;r<4;r++)
      inv[r] = 1.f/(SredS[mt][0][quad*4+r] + SredS[mt][1][quad*4+r]
                  + SredS[mt][2][quad*4+r] + SredS[mt][3][quad*4+r]);
    // write P (swizzled) + PT (packed b64); rows q>196 forced 0
    for(int ni=0; ni<ncnt; ni++){
      int j = (nt0s+ni)*16 + lane16;
      short4v pk;
      #pragma unroll
      for(int r=0;r<4;r++){
        int q = 16*mt + quad*4 + r;
        float val = (q0 + q <= 196) ? sa[ni][r]*inv[r] : 0.f;
        u16 hv = f2bf(val);
        P[q*256 + 8*((j>>3)^(q&7)) + (j&7)] = hv;
        pk[r] = (short)hv;
      }
      *(short4v*)&PT[j*40 + 16*mt + 4*quad] = pk;
    }
    // zero P logical cols 208..223 (read by Gq kt=6 upper quads)
    for(int idx=tid; idx<32*16; idx+=512){
      int q = idx>>4, j = 208 + (idx&15);
      P[q*256 + 8*((j>>3)^(q&7)) + (j&7)] = 0;
    }
    __syncthreads();
    // ---- Gq = P K : one 16x16 tile per wave (mt x nh), B-frags from KTl
    {
      f32x4 gq = (f32x4){0.f,0.f,0.f,0.f};
      int qrow = 16*mt + lane16;
      int z = nh*16 + lane16;
      for(int kt=0; kt<7; kt++){
        short8 af = *(const short8*)&P[qrow*256 + 8*((4*kt+quad)^(qrow&7))];
        short8 bf8 = *(const short8*)&KTl[z*232 + kt*32 + quad*8];
        gq = __builtin_amdgcn_mfma_f32_16x16x32_bf16(af, bf8, gq,0,0,0);
      }
      #pragma unroll
      for(int r=0;r<4;r++){
        int qg2 = q0 + 16*mt + quad*4 + r;
        if(qg2 <= 196) Qg[(size_t)qg2*768 + nh*16 + lane16] = f2bf(gq[r]);
      }
    }
    // ---- Gk accumulate: A-frags from PT, B-frags from QTl
    {
      short8 bq2[4];
      #pragma unroll
      for(int n2=0;n2<4;n2++)
        bq2[n2] = *(const short8*)&QTl[(n2*16+lane16)*232 + q0 + quad*8];
      for(int ji=0; ji<jn; ji++){
        int j = (jt0+ji)*16 + lane16;
        short8 af = *(const short8*)&PT[j*40 + quad*8];
        #pragma unroll
        for(int n2=0;n2<4;n2++)
          gk[ji][n2] = __builtin_amdgcn_mfma_f32_16x16x32_bf16(af, bq2[n2], gk[ji][n2],0,0,0);
      }
    }
  }
  __syncthreads();
  for(int ji=0; ji<jn; ji++){
    int jt = jt0 + ji;
    #pragma unroll
    for(int n2=0;n2<4;n2++)
      #pragma unroll
      for(int r=0;r<4;r++){
        int j = jt*16 + quad*4 + r;
        if(j <= 196) Kg[(size_t)j*768 + n2*16 + lane16] = f2bf(gk[ji][n2][r]);
      }
  }
}

// ---------------- small utility kernels ----------------
__global__ void cvt_k(const float* __restrict__ in, u16* __restrict__ out, int n){
  for(int i=blockIdx.x*256+threadIdx.x; i<n; i+=gridDim.x*256) out[i] = f2bf(in[i]);
}

// dst[c*dstride + coff + r] = bf16(src[r*C + c]); R,C multiples of 32
__global__ __launch_bounds__(256)
void tr_k(const float* __restrict__ src, u16* __restrict__ dst, int R, int C, int dstride, int coff){
  __shared__ float tile[32][33];
  int c0 = blockIdx.x*32, r0 = blockIdx.y*32;
  int tx = threadIdx.x & 31, ty = threadIdx.x >> 5;
  for(int i=ty;i<32;i+=8) tile[i][tx] = src[(size_t)(r0+i)*C + c0 + tx];
  __syncthreads();
  for(int i=ty;i<32;i+=8) dst[(size_t)(c0+i)*dstride + coff + r0 + tx] = f2bf(tile[tx][i]);
}

__global__ void fill_cls_k(float* __restrict__ t, const float* __restrict__ cls, const float* __restrict__ pos){
  int b = blockIdx.x;
  for(int i=threadIdx.x;i<768;i+=256) t[(size_t)b*197*768 + i] = cls[i] + pos[i];
}

// ---------------- launch ----------------
extern "C" void kernel_launch(void* const* d_in, const int* in_sizes, int n_in,
                              void* d_out, int out_size, void* d_ws, size_t ws_size,
                              hipStream_t stream){
  const float* x      = (const float*)d_in[0];
  const float* W_enc  = (const float*)d_in[1];
  const float* b_enc  = (const float*)d_in[2];
  const float* cls    = (const float*)d_in[3];
  const float* pos    = (const float*)d_in[4];
  const float* gamma  = (const float*)d_in[5];
  const float* bias   = (const float*)d_in[6];
  const float* Wq     = (const float*)d_in[7];
  const float* Wk     = (const float*)d_in[8];
  const float* Whn    = (const float*)d_in[9];
  const float* araw   = (const float*)d_in[10];
  const float* ln_g   = (const float*)d_in[11];
  const float* ln_b   = (const float*)d_in[12];
  const float* W_dec  = (const float*)d_in[13];
  const float* b_dec  = (const float*)d_in[14];
  float* out = (float*)d_out;
  (void)in_sizes; (void)n_in; (void)out_size;

  const int M  = 64*197;   // 12608
  const int MX = 64*196;   // 12544

  // ---- workspace ----
  char* p = (char*)d_ws;
  float* t   = (float*)p;  p += (size_t)M*768*4;        // 38.7 MB
  u16*   g   = (u16*)p;    p += (size_t)M*768*2;        // 19.4 MB (LN out)
  u16*   Qb  = (u16*)p;    p += (size_t)M*768*2;        // 19.4 MB (Gq out; xb overlay)
  u16*   Kb  = (u16*)p;    p += (size_t)M*768*2;        // 19.4 MB (Gk out; WencT/WdecT overlay)
  size_t base = (size_t)(p - (char*)d_ws);
  if(base > ws_size) return;
  // merged-hopfield hidden buffer (77.46 MB) if it fits, else 2-chunk overlay on Qb/Kb
  u16* hidden; int hop_merged;
  if(base + (size_t)M*3072*2 <= ws_size){ hidden = (u16*)(d_ws) + base/2; hop_merged = 1; }
  else { hidden = Qb; hop_merged = 0; }

  // ---- weights live inside d_out (28.3 MB of 38.5 MB; fully dead before decode write) ----
  u16* Wall = (u16*)d_out;
  u16* Wqkb = Wall;               // 2 x [Wq(768 rows); Wk(768 rows)] x 768
  u16* WqkT = Wall + 2359296;     // 2 x 768 x [WqT | WkT] (stride 1536)
  u16* WhnT = Wall + 4718592;     // 2 x 3072 x 768
  u16* WhnB = Wall + 9437184;     // 2 x 768 x 3072 (row-major, ldb 3072)
  u16* xb    = Qb;                // encode-time overlay
  u16* WencT = Kb;                // encode-time overlay
  u16* WdecT = Kb;                // decode-time overlay

  // ---- weight prep ----
  for(int b=0;b<2;b++){
    cvt_k<<<512,256,0,stream>>>(Wq + (size_t)b*589824, Wqkb + (size_t)b*1179648, 589824);
    cvt_k<<<512,256,0,stream>>>(Wk + (size_t)b*589824, Wqkb + (size_t)b*1179648 + 589824, 589824);
    tr_k<<<dim3(24,24),256,0,stream>>>(Wq + (size_t)b*589824, WqkT + (size_t)b*1179648, 768,768, 1536, 0);
    tr_k<<<dim3(24,24),256,0,stream>>>(Wk + (size_t)b*589824, WqkT + (size_t)b*1179648, 768,768, 1536, 768);
    tr_k<<<dim3(96,24),256,0,stream>>>(Whn + (size_t)b*2359296, WhnT + (size_t)b*2359296, 768,3072, 768, 0);
    cvt_k<<<2048,256,0,stream>>>(Whn + (size_t)b*2359296, WhnB + (size_t)b*2359296, 2359296);
  }

  // ---- encode: t = [cls; x@W_enc + b_enc] + pos ----
  cvt_k<<<1024,256,0,stream>>>(x, xb, MX*768);
  tr_k<<<dim3(24,24),256,0,stream>>>(W_enc, WencT, 768,768, 768, 0);
  fill_cls_k<<<64,256,0,stream>>>(t, cls, pos);
  gemm_bt<3,0><<<dim3(6,98),256,0,stream>>>(xb, nullptr, WencT, nullptr, t,
                                            MX, 768, 768, 768, 768,
                                            b_enc, pos, nullptr, 0);

  // ---- energy-descent blocks ----
  for(int blk=0; blk<2; blk++){
    for(int s=0; s<4; s++){
      norm_k<<<M,256,0,stream>>>(t, g, gamma, bias, blk, 0);
      if(hop_merged){
        gemm_bt<1,0><<<dim3(24,99),256,0,stream>>>(g, nullptr,
            WhnT + (size_t)blk*2359296,
            hidden, nullptr, M, 3072, 768, 768, 3072,
            nullptr, nullptr, nullptr, 0);
        gemm_bt<2,0><<<dim3(6,99),256,0,stream>>>(hidden, nullptr,
            WhnB + (size_t)blk*2359296,
            nullptr, t, M, 768, 3072, 3072, 768,
            nullptr, nullptr, araw, blk);
      } else {
        for(int c=0;c<2;c++){
          gemm_bt<1,0><<<dim3(12,99),256,0,stream>>>(g, nullptr,
              WhnT + (size_t)blk*2359296 + (size_t)c*1536*768,
              hidden, nullptr, M, 1536, 768, 768, 1536,
              nullptr, nullptr, nullptr, 0);
          gemm_bt<2,0><<<dim3(6,99),256,0,stream>>>(hidden, nullptr,
              WhnB + (size_t)blk*2359296 + (size_t)c*1536,
              nullptr, t, M, 768, 1536, 3072, 768,
              nullptr, nullptr, araw, blk);
        }
      }
      // fused QK-projection + attention: reads g + Wqk, writes Gq -> Qb, Gk -> Kb
      attn_fused<<<768,512,0,stream>>>(g, Wqkb + (size_t)blk*1179648, Qb, Kb);
      // gradient projection (merged K=1536, split-A: A=Gq(Qb), A2=Gk(Kb))
      gemm_bt<2,1><<<dim3(6,99),256,0,stream>>>(Qb, Kb, WqkT + (size_t)blk*1179648,
            nullptr, t, M, 768, 1536, 1536, 768,
            nullptr, nullptr, araw, blk);
    }
  }

  // ---- decode: LN -> GEMM -> drop CLS ----
  tr_k<<<dim3(24,24),256,0,stream>>>(W_dec, WdecT, 768,768, 768, 0);
  norm_k<<<M,256,0,stream>>>(t, g, ln_g, ln_b, 0, 1);
  gemm_bt<4,0><<<dim3(6,99),256,0,stream>>>(g, nullptr, WdecT, nullptr, out,
                                            M, 768, 768, 768, 768,
                                            b_dec, nullptr, nullptr, 0);
}